// Round 8
// baseline (800.999 us; speedup 1.0000x reference)
//
#include <hip/hip_runtime.h>
#include <math.h>

#define Nn 512
#define Tt 8
#define Ee 16384
#define NNc (Nn*Nn)          // 262144
#define TNr (Tt*Nn)          // 4096
#define TE  (Tt*Ee)          // 131072
#define CAP 128              // bucket capacity per (t,dst); Poisson(32) => overflow ~1e-35

// ---------------- fused feat_proj + WLE layer1
__global__ __launch_bounds__(256) void k_fp1(
    const float* __restrict__ feats, const float* __restrict__ noise,
    const float* __restrict__ Wp1, const float* __restrict__ bp1,
    const float* __restrict__ Wp2, const float* __restrict__ bp2,
    const float* __restrict__ W1, const float* __restrict__ b1,
    float* __restrict__ hh)
{
    __shared__ float sfeat[16][128];
    __shared__ float sh1[16][256];
    __shared__ float semb[16][80];
    int tid = threadIdx.x;
    int r0 = blockIdx.x * 16;
#pragma unroll
    for (int k = 0; k < 8; ++k) {
        int lin = k*256 + tid;
        sfeat[lin>>7][lin&127] = feats[(size_t)r0*128 + lin];
    }
    {
        int r = tid>>4, k = tid&15;
        semb[r][64+k] = noise[(size_t)(r0+r)*16 + k];
    }
    __syncthreads();
    {
        int j = tid;
        float acc[16];
#pragma unroll
        for (int r=0;r<16;++r) acc[r]=0.f;
        for (int i=0;i<128;i+=4) {
            float w0=Wp1[(i+0)*256+j], w1=Wp1[(i+1)*256+j];
            float w2=Wp1[(i+2)*256+j], w3=Wp1[(i+3)*256+j];
#pragma unroll
            for (int r=0;r<16;++r) {
                float4 f = *(const float4*)&sfeat[r][i];
                acc[r] += f.x*w0 + f.y*w1 + f.z*w2 + f.w*w3;
            }
        }
        float b = bp1[j];
#pragma unroll
        for (int r=0;r<16;++r) sh1[r][j] = fmaxf(acc[r]+b, 0.f);
    }
    __syncthreads();
    {
        int jo = tid & 63;
        int rr = tid >> 6;
        float b2v = bp2[jo];
        for (int rg=0; rg<4; ++rg) {
            int r = rg*4 + rr;
            float a2 = 0.f;
            for (int i=0;i<256;i+=4) {
                float4 f = *(const float4*)&sh1[r][i];
                a2 += f.x*Wp2[(i+0)*64+jo] + f.y*Wp2[(i+1)*64+jo]
                    + f.z*Wp2[(i+2)*64+jo] + f.w*Wp2[(i+3)*64+jo];
            }
            semb[r][jo] = fmaxf(a2+b2v, 0.f);
        }
    }
    __syncthreads();
    {
        int j = tid & 127;
        int rb = (tid>>7)*8;
        float acc[8];
#pragma unroll
        for (int r=0;r<8;++r) acc[r]=0.f;
        for (int i=0;i<80;i+=4) {
            float w0=W1[(i+0)*128+j], w1=W1[(i+1)*128+j];
            float w2=W1[(i+2)*128+j], w3=W1[(i+3)*128+j];
#pragma unroll
            for (int r=0;r<8;++r) {
                float4 f = *(const float4*)&semb[rb+r][i];
                acc[r] += f.x*w0 + f.y*w1 + f.z*w2 + f.w*w3;
            }
        }
        float b = b1[j];
#pragma unroll
        for (int r=0;r<8;++r) hh[(size_t)(r0+rb+r)*128 + j] = fmaxf(acc[r]+b, 0.f);
    }
}

// ---------------- one edge pass: bucket-CSR build + last-write-wins tag
__global__ __launch_bounds__(256) void k_histtag(
    const int* __restrict__ ei, int* __restrict__ cnt,
    int* __restrict__ bucket, int* __restrict__ tag)
{
    int g = blockIdx.x*256 + threadIdx.x;       // < T*E
    int t = g>>14, e = g&(Ee-1);
    int a = ei[t*2*Ee + e];                     // dst
    int b = ei[t*2*Ee + Ee + e];                // src
    int cell = t*Nn + a;
    int pos = atomicAdd(&cnt[cell], 1);
    if (pos < CAP) bucket[cell*CAP + pos] = e;
    atomicMax(&tag[t*NNc + a*Nn + b], g+1);
}

// ---------------- agg[t,dst,:] = hh[t,dst,:] + sum_{e in bucket} ew[e]*hh[t,src(e),:]
__global__ __launch_bounds__(128) void k_scatter2(
    const int* __restrict__ ei, const float* __restrict__ ew,
    const float* __restrict__ hh, const int* __restrict__ cnt,
    const int* __restrict__ bucket, float* __restrict__ agg)
{
    int bid = blockIdx.x;            // < T*Nn
    int t = bid >> 9;
    int ch = threadIdx.x;
    int n = cnt[bid]; n = n < CAP ? n : CAP;
    const int* __restrict__ bk = &bucket[(size_t)bid*CAP];
    const int* __restrict__ eis = &ei[t*2*Ee + Ee];
    const float* __restrict__ ewt = &ew[t*Ee];
    const float* __restrict__ hht = &hh[(size_t)t*Nn*128];
    float acc = hh[(size_t)bid*128 + ch];       // include the +hh term here
    int i = 0;
    for (; i+1 < n; i += 2){
        int e0 = bk[i], e1 = bk[i+1];
        int s0 = eis[e0], s1 = eis[e1];
        float w0 = ewt[e0], w1 = ewt[e1];
        acc += w0*hht[(size_t)s0*128 + ch] + w1*hht[(size_t)s1*128 + ch];
    }
    if (i < n){
        int e0 = bk[i];
        acc += ewt[e0]*hht[(size_t)eis[e0]*128 + ch];
    }
    agg[(size_t)bid*128 + ch] = acc;
}

// ---------------- h2 = relu(agg @ W2[128,128] + b2)   (agg already includes hh)
__global__ __launch_bounds__(256) void k_wle2(
    const float* __restrict__ agg,
    const float* __restrict__ W2, const float* __restrict__ b2,
    float* __restrict__ h2)
{
    __shared__ float sx[16][128];
    int tid=threadIdx.x; int r0=blockIdx.x*16;
#pragma unroll
    for (int k=0;k<8;++k){
        int lin=k*256+tid;
        sx[lin>>7][lin&127]=agg[(size_t)r0*128+lin];
    }
    __syncthreads();
    int j=tid&127; int rb=(tid>>7)*8;
    float acc[8];
#pragma unroll
    for(int r=0;r<8;++r)acc[r]=0.f;
    for(int i=0;i<128;i+=4){
        float w0=W2[(i+0)*128+j], w1=W2[(i+1)*128+j];
        float w2v=W2[(i+2)*128+j], w3=W2[(i+3)*128+j];
#pragma unroll
        for(int r=0;r<8;++r){
            float4 f=*(const float4*)&sx[rb+r][i];
            acc[r]+=f.x*w0+f.y*w1+f.z*w2v+f.w*w3;
        }
    }
    float b=b2[j];
#pragma unroll
    for(int r=0;r<8;++r) h2[(size_t)(r0+rb+r)*128+j]=fmaxf(acc[r]+b,0.f);
}

// ---------------- edge scores, 8e x 16j per thread, KC=16 (25KB LDS -> 4 blocks/CU)
#define KC 16
__global__ __launch_bounds__(256, 4) void k_edge7(
    const int* __restrict__ ei, const float* __restrict__ h2,
    const float* __restrict__ W3, const float* __restrict__ b3,
    const float* __restrict__ w4, const float* __restrict__ b4,
    float* __restrict__ sc)
{
    __shared__ float sE[KC*264];      // 16896 B
    __shared__ float sW[KC*128];      // 8192 B
    int tid = threadIdx.x;
    int bid = blockIdx.x;             // < TE/256 = 512
    int tb  = bid >> 6;               // timestep (64 blocks per t)
    int ein = (bid & 63)*256 + tid;   // this thread's staged edge
    int a = ei[tb*2*Ee + ein];
    int b = ei[tb*2*Ee + Ee + ein];
    const float4* __restrict__ pa = (const float4*)&h2[((size_t)(tb*Nn+a))*128];
    const float4* __restrict__ pb = (const float4*)&h2[((size_t)(tb*Nn+b))*128];

    int tx = tid & 7, ty = tid >> 3;  // tx: j-groups, ty: e-groups
    int e0 = ty*8;
    int jA = tx*4, jB = 32+tx*4, jC = 64+tx*4, jD = 96+tx*4;
    float4 b3A = *(const float4*)&b3[jA];
    float4 b3B = *(const float4*)&b3[jB];
    float4 b3C = *(const float4*)&b3[jC];
    float4 b3D = *(const float4*)&b3[jD];
    float4 w4A = *(const float4*)&w4[jA];
    float4 w4B = *(const float4*)&w4[jB];
    float4 w4C = *(const float4*)&w4[jC];
    float4 w4D = *(const float4*)&w4[jD];

    float acc[8][16];
#pragma unroll
    for (int i=0;i<8;++i)
#pragma unroll
        for (int j=0;j<16;++j) acc[i][j]=0.f;

    for (int c=0;c<8;++c){
        int k0 = c*KC;
        __syncthreads();
        // stage W chunk [KC][128] (linear, coalesced): 512 float4 / 256 thr
        {
            const float4* __restrict__ src = (const float4*)&W3[k0*128];
            float4* dst = (float4*)sW;
#pragma unroll
            for (int q=0;q<2;++q) dst[q*256+tid] = src[q*256+tid];
        }
        // stage ef chunk transposed: this thread fills column `tid` for 16 k's
        {
            int kg = k0 >> 2;
#pragma unroll
            for (int q=0;q<4;++q){
                float4 x = pa[kg+q], y = pb[kg+q];
                sE[(q*4+0)*264 + tid] = x.x*y.x;
                sE[(q*4+1)*264 + tid] = x.y*y.y;
                sE[(q*4+2)*264 + tid] = x.z*y.z;
                sE[(q*4+3)*264 + tid] = x.w*y.w;
            }
        }
        __syncthreads();
#pragma unroll 8
        for (int kk=0;kk<KC;++kk){
            float4 ea = *(const float4*)&sE[kk*264 + e0];
            float4 eb = *(const float4*)&sE[kk*264 + e0 + 4];
            float4 wA = *(const float4*)&sW[kk*128 + jA];
            float4 wB = *(const float4*)&sW[kk*128 + jB];
            float4 wC = *(const float4*)&sW[kk*128 + jC];
            float4 wD = *(const float4*)&sW[kk*128 + jD];
            float ev0=ea.x, ev1=ea.y, ev2=ea.z, ev3=ea.w;
            float ev4=eb.x, ev5=eb.y, ev6=eb.z, ev7=eb.w;
#define ROW(i, ev) \
            acc[i][0]+=ev*wA.x;  acc[i][1]+=ev*wA.y;  acc[i][2]+=ev*wA.z;  acc[i][3]+=ev*wA.w; \
            acc[i][4]+=ev*wB.x;  acc[i][5]+=ev*wB.y;  acc[i][6]+=ev*wB.z;  acc[i][7]+=ev*wB.w; \
            acc[i][8]+=ev*wC.x;  acc[i][9]+=ev*wC.y;  acc[i][10]+=ev*wC.z; acc[i][11]+=ev*wC.w; \
            acc[i][12]+=ev*wD.x; acc[i][13]+=ev*wD.y; acc[i][14]+=ev*wD.z; acc[i][15]+=ev*wD.w;
            ROW(0,ev0) ROW(1,ev1) ROW(2,ev2) ROW(3,ev3)
            ROW(4,ev4) ROW(5,ev5) ROW(6,ev6) ROW(7,ev7)
#undef ROW
        }
    }
    float b4v = b4[0];
#pragma unroll
    for (int i=0;i<8;++i){
        float p = fmaxf(acc[i][0]+b3A.x,0.f)*w4A.x
                + fmaxf(acc[i][1]+b3A.y,0.f)*w4A.y
                + fmaxf(acc[i][2]+b3A.z,0.f)*w4A.z
                + fmaxf(acc[i][3]+b3A.w,0.f)*w4A.w
                + fmaxf(acc[i][4]+b3B.x,0.f)*w4B.x
                + fmaxf(acc[i][5]+b3B.y,0.f)*w4B.y
                + fmaxf(acc[i][6]+b3B.z,0.f)*w4B.z
                + fmaxf(acc[i][7]+b3B.w,0.f)*w4B.w
                + fmaxf(acc[i][8]+b3C.x,0.f)*w4C.x
                + fmaxf(acc[i][9]+b3C.y,0.f)*w4C.y
                + fmaxf(acc[i][10]+b3C.z,0.f)*w4C.z
                + fmaxf(acc[i][11]+b3C.w,0.f)*w4C.w
                + fmaxf(acc[i][12]+b3D.x,0.f)*w4D.x
                + fmaxf(acc[i][13]+b3D.y,0.f)*w4D.y
                + fmaxf(acc[i][14]+b3D.z,0.f)*w4D.z
                + fmaxf(acc[i][15]+b3D.w,0.f)*w4D.w;
        p += __shfl_xor(p,1);
        p += __shfl_xor(p,2);
        p += __shfl_xor(p,4);
        if (tx==0) sc[bid*256 + e0 + i] = p + b4v;
    }
}

// ---------------- SSM recurrence (reads tag+sc directly)
__global__ __launch_bounds__(256) void k_ssm2(
    const int* __restrict__ ei, const int* __restrict__ tag,
    const float* __restrict__ sc,
    const float* __restrict__ W_in, const float* __restrict__ conv_w,
    const float* __restrict__ conv_b, const float* __restrict__ dt_bias,
    const float* __restrict__ A_log, const float* __restrict__ D_skip,
    const float* __restrict__ W_out, float* __restrict__ out)
{
    __shared__ float scw[132], scb[33], swin[35];
    int tid = threadIdx.x;
    if (tid < 132) scw[tid] = conv_w[tid];
    if (tid < 33)  scb[tid] = conv_b[tid];
    if (tid < 35)  swin[tid] = W_in[tid];
    __syncthreads();

    int e = blockIdx.x*256 + tid;              // < E
    int a = ei[7*2*Ee + e], b = ei[7*2*Ee + Ee + e];
    int cell = a*Nn + b;
    float x[8];
#pragma unroll
    for (int t=0;t<8;++t){
        int tg = tag[t*NNc + cell];
        x[t] = (tg > 0) ? sc[tg-1] : 0.f;
    }

    float A    = -expf(A_log[0]);
    float dtb  = dt_bias[0];
    float dsk  = D_skip[0];
    float wout = W_out[0];
    float win_z = swin[0], win_dt = swin[34];

    float ssm[16];
#pragma unroll
    for (int q=0;q<16;++q) ssm[q]=0.f;
    float h0=0.f,h1=0.f,h2v=0.f;
    float y=0.f;
    for (int t=0;t<8;++t){
        float xt = x[t];
        float act[33];
#pragma unroll
        for (int c=0;c<33;++c){
            float s = h0*scw[c*4+0] + h1*scw[c*4+1] + h2v*scw[c*4+2] + xt*scw[c*4+3];
            float pre = swin[1+c]*s + scb[c];
            act[c] = pre / (1.f + expf(-pre));
        }
        float x_ = act[0];
        float dtr = xt*win_dt + dtb;
        float dt  = (dtr > 20.f) ? dtr : log1pf(expf(dtr));
        float dA  = expf(dt*A);
        float dx  = dt*x_;
        float yv = 0.f;
#pragma unroll
        for (int q=0;q<16;++q){
            ssm[q] = ssm[q]*dA + dx*act[1+q];
            yv += ssm[q]*act[17+q];
        }
        yv += dsk*x_;
        float z = xt*win_z;
        yv *= z / (1.f + expf(-z));
        y = yv;
        h0=h1; h1=h2v; h2v=xt;
    }
    out[cell] = y*wout;
}

extern "C" void kernel_launch(void* const* d_in, const int* in_sizes, int n_in,
                              void* d_out, int out_size, void* d_ws, size_t ws_size,
                              hipStream_t stream)
{
    const int*   ei    = (const int*)d_in[0];
    const float* ew    = (const float*)d_in[1];
    const float* feats = (const float*)d_in[2];
    const float* noise = (const float*)d_in[3];
    const float* Wp1=(const float*)d_in[4];  const float* bp1=(const float*)d_in[5];
    const float* Wp2=(const float*)d_in[6];  const float* bp2=(const float*)d_in[7];
    const float* W1 =(const float*)d_in[8];  const float* b1 =(const float*)d_in[9];
    const float* W2 =(const float*)d_in[10]; const float* b2 =(const float*)d_in[11];
    const float* W3 =(const float*)d_in[12]; const float* b3 =(const float*)d_in[13];
    const float* w4 =(const float*)d_in[14]; const float* b4 =(const float*)d_in[15];
    const float* W_in  =(const float*)d_in[16]; const float* conv_w=(const float*)d_in[17];
    const float* conv_b=(const float*)d_in[18]; const float* dt_bias=(const float*)d_in[19];
    const float* A_log =(const float*)d_in[20]; const float* D_skip=(const float*)d_in[21];
    const float* W_out =(const float*)d_in[22];

    float* out = (float*)d_out;
    float* ws  = (float*)d_ws;
    float* hh    = ws;                      // T*N*128  = 524288
    float* agg   = hh    + 524288;          // 524288
    float* h2    = agg   + 524288;          // 524288
    float* sc    = h2    + 524288;          // T*E      = 131072
    int*   cnt   = (int*)(sc + 131072);     // T*N      = 4096   (contiguous with tag)
    int*   tag   = cnt + TNr;               // T*N*N    = 2097152
    int*   bucket= tag + 2097152;           // T*N*CAP  = 524288

    hipMemsetAsync(out, 0, (size_t)NNc*4, stream);
    hipMemsetAsync(cnt, 0, (size_t)(TNr + 2097152)*4, stream);   // cnt + tag in one blit

    k_histtag <<<TE/256, 256, 0, stream>>>(ei, cnt, bucket, tag);
    k_fp1     <<<TNr/16, 256, 0, stream>>>(feats, noise, Wp1, bp1, Wp2, bp2, W1, b1, hh);
    k_scatter2<<<TNr, 128, 0, stream>>>(ei, ew, hh, cnt, bucket, agg);
    k_wle2    <<<TNr/16, 256, 0, stream>>>(agg, W2, b2, h2);
    k_edge7   <<<TE/256, 256, 0, stream>>>(ei, h2, W3, b3, w4, b4, sc);
    k_ssm2    <<<Ee/256, 256, 0, stream>>>(ei, tag, sc, W_in, conv_w, conv_b,
                                           dt_bias, A_log, D_skip, W_out, out);
}

// Round 9
// 167.967 us; speedup vs baseline: 4.7688x; 4.7688x over previous
//
#include <hip/hip_runtime.h>
#include <math.h>

#define Nn 512
#define Tt 8
#define Ee 16384
#define NNc (Nn*Nn)          // 262144
#define TNr (Tt*Nn)          // 4096
#define TE  (Tt*Ee)          // 131072
#define CAP 128              // bucket capacity per (t,dst); Poisson(32) => overflow ~1e-35

// ---------------- fused feat_proj + WLE layer1
__global__ __launch_bounds__(256) void k_fp1(
    const float* __restrict__ feats, const float* __restrict__ noise,
    const float* __restrict__ Wp1, const float* __restrict__ bp1,
    const float* __restrict__ Wp2, const float* __restrict__ bp2,
    const float* __restrict__ W1, const float* __restrict__ b1,
    float* __restrict__ hh)
{
    __shared__ float sfeat[16][128];
    __shared__ float sh1[16][256];
    __shared__ float semb[16][80];
    int tid = threadIdx.x;
    int r0 = blockIdx.x * 16;
#pragma unroll
    for (int k = 0; k < 8; ++k) {
        int lin = k*256 + tid;
        sfeat[lin>>7][lin&127] = feats[(size_t)r0*128 + lin];
    }
    {
        int r = tid>>4, k = tid&15;
        semb[r][64+k] = noise[(size_t)(r0+r)*16 + k];
    }
    __syncthreads();
    {
        int j = tid;
        float acc[16];
#pragma unroll
        for (int r=0;r<16;++r) acc[r]=0.f;
        for (int i=0;i<128;i+=4) {
            float w0=Wp1[(i+0)*256+j], w1=Wp1[(i+1)*256+j];
            float w2=Wp1[(i+2)*256+j], w3=Wp1[(i+3)*256+j];
#pragma unroll
            for (int r=0;r<16;++r) {
                float4 f = *(const float4*)&sfeat[r][i];
                acc[r] += f.x*w0 + f.y*w1 + f.z*w2 + f.w*w3;
            }
        }
        float b = bp1[j];
#pragma unroll
        for (int r=0;r<16;++r) sh1[r][j] = fmaxf(acc[r]+b, 0.f);
    }
    __syncthreads();
    {
        int jo = tid & 63;
        int rr = tid >> 6;
        float b2v = bp2[jo];
        for (int rg=0; rg<4; ++rg) {
            int r = rg*4 + rr;
            float a2 = 0.f;
            for (int i=0;i<256;i+=4) {
                float4 f = *(const float4*)&sh1[r][i];
                a2 += f.x*Wp2[(i+0)*64+jo] + f.y*Wp2[(i+1)*64+jo]
                    + f.z*Wp2[(i+2)*64+jo] + f.w*Wp2[(i+3)*64+jo];
            }
            semb[r][jo] = fmaxf(a2+b2v, 0.f);
        }
    }
    __syncthreads();
    {
        int j = tid & 127;
        int rb = (tid>>7)*8;
        float acc[8];
#pragma unroll
        for (int r=0;r<8;++r) acc[r]=0.f;
        for (int i=0;i<80;i+=4) {
            float w0=W1[(i+0)*128+j], w1=W1[(i+1)*128+j];
            float w2=W1[(i+2)*128+j], w3=W1[(i+3)*128+j];
#pragma unroll
            for (int r=0;r<8;++r) {
                float4 f = *(const float4*)&semb[rb+r][i];
                acc[r] += f.x*w0 + f.y*w1 + f.z*w2 + f.w*w3;
            }
        }
        float b = b1[j];
#pragma unroll
        for (int r=0;r<8;++r) hh[(size_t)(r0+rb+r)*128 + j] = fmaxf(acc[r]+b, 0.f);
    }
}

// ---------------- one edge pass: bucket-CSR build + last-write-wins tag
__global__ __launch_bounds__(256) void k_histtag(
    const int* __restrict__ ei, int* __restrict__ cnt,
    int* __restrict__ bucket, int* __restrict__ tag)
{
    int g = blockIdx.x*256 + threadIdx.x;       // < T*E
    int t = g>>14, e = g&(Ee-1);
    int a = ei[t*2*Ee + e];                     // dst
    int b = ei[t*2*Ee + Ee + e];                // src
    int cell = t*Nn + a;
    int pos = atomicAdd(&cnt[cell], 1);
    if (pos < CAP) bucket[cell*CAP + pos] = e;
    atomicMax(&tag[t*NNc + a*Nn + b], g+1);
}

// ---------------- agg[t,dst,:] = hh[t,dst,:] + sum_{e in bucket} ew[e]*hh[t,src(e),:]
__global__ __launch_bounds__(128) void k_scatter2(
    const int* __restrict__ ei, const float* __restrict__ ew,
    const float* __restrict__ hh, const int* __restrict__ cnt,
    const int* __restrict__ bucket, float* __restrict__ agg)
{
    int bid = blockIdx.x;            // < T*Nn
    int t = bid >> 9;
    int ch = threadIdx.x;
    int n = cnt[bid]; n = n < CAP ? n : CAP;
    const int* __restrict__ bk = &bucket[(size_t)bid*CAP];
    const int* __restrict__ eis = &ei[t*2*Ee + Ee];
    const float* __restrict__ ewt = &ew[t*Ee];
    const float* __restrict__ hht = &hh[(size_t)t*Nn*128];
    float acc = hh[(size_t)bid*128 + ch];       // include the +hh term here
    int i = 0;
    for (; i+1 < n; i += 2){
        int e0 = bk[i], e1 = bk[i+1];
        int s0 = eis[e0], s1 = eis[e1];
        float w0 = ewt[e0], w1 = ewt[e1];
        acc += w0*hht[(size_t)s0*128 + ch] + w1*hht[(size_t)s1*128 + ch];
    }
    if (i < n){
        int e0 = bk[i];
        acc += ewt[e0]*hht[(size_t)eis[e0]*128 + ch];
    }
    agg[(size_t)bid*128 + ch] = acc;
}

// ---------------- h2 = relu(agg @ W2[128,128] + b2)   (agg already includes hh)
__global__ __launch_bounds__(256) void k_wle2(
    const float* __restrict__ agg,
    const float* __restrict__ W2, const float* __restrict__ b2,
    float* __restrict__ h2)
{
    __shared__ float sx[16][128];
    int tid=threadIdx.x; int r0=blockIdx.x*16;
#pragma unroll
    for (int k=0;k<8;++k){
        int lin=k*256+tid;
        sx[lin>>7][lin&127]=agg[(size_t)r0*128+lin];
    }
    __syncthreads();
    int j=tid&127; int rb=(tid>>7)*8;
    float acc[8];
#pragma unroll
    for(int r=0;r<8;++r)acc[r]=0.f;
    for(int i=0;i<128;i+=4){
        float w0=W2[(i+0)*128+j], w1=W2[(i+1)*128+j];
        float w2v=W2[(i+2)*128+j], w3=W2[(i+3)*128+j];
#pragma unroll
        for(int r=0;r<8;++r){
            float4 f=*(const float4*)&sx[rb+r][i];
            acc[r]+=f.x*w0+f.y*w1+f.z*w2v+f.w*w3;
        }
    }
    float b=b2[j];
#pragma unroll
    for(int r=0;r<8;++r) h2[(size_t)(r0+rb+r)*128+j]=fmaxf(acc[r]+b,0.f);
}

// ---------------- edge scores, 8e x 16j per thread, KC=16 (25KB LDS)
// launch_bounds(256,2): compiler lands ~116 VGPR (as k_edge6 did) -> 4 waves/SIMD
// naturally; do NOT force 4 waves (that caps VGPR at 128 and spills acc -> R8's 800us).
#define KC 16
__global__ __launch_bounds__(256, 2) void k_edge7(
    const int* __restrict__ ei, const float* __restrict__ h2,
    const float* __restrict__ W3, const float* __restrict__ b3,
    const float* __restrict__ w4, const float* __restrict__ b4,
    float* __restrict__ sc)
{
    __shared__ float sE[KC*264];      // 16896 B
    __shared__ float sW[KC*128];      // 8192 B
    int tid = threadIdx.x;
    int bid = blockIdx.x;             // < TE/256 = 512
    int tb  = bid >> 6;               // timestep (64 blocks per t)
    int ein = (bid & 63)*256 + tid;   // this thread's staged edge
    int a = ei[tb*2*Ee + ein];
    int b = ei[tb*2*Ee + Ee + ein];
    const float4* __restrict__ pa = (const float4*)&h2[((size_t)(tb*Nn+a))*128];
    const float4* __restrict__ pb = (const float4*)&h2[((size_t)(tb*Nn+b))*128];

    int tx = tid & 7, ty = tid >> 3;  // tx: j-groups, ty: e-groups
    int e0 = ty*8;
    int jA = tx*4, jB = 32+tx*4, jC = 64+tx*4, jD = 96+tx*4;
    float4 b3A = *(const float4*)&b3[jA];
    float4 b3B = *(const float4*)&b3[jB];
    float4 b3C = *(const float4*)&b3[jC];
    float4 b3D = *(const float4*)&b3[jD];
    float4 w4A = *(const float4*)&w4[jA];
    float4 w4B = *(const float4*)&w4[jB];
    float4 w4C = *(const float4*)&w4[jC];
    float4 w4D = *(const float4*)&w4[jD];

    float acc[8][16];
#pragma unroll
    for (int i=0;i<8;++i)
#pragma unroll
        for (int j=0;j<16;++j) acc[i][j]=0.f;

    for (int c=0;c<8;++c){
        int k0 = c*KC;
        __syncthreads();
        // stage W chunk [KC][128] (linear, coalesced): 512 float4 / 256 thr
        {
            const float4* __restrict__ src = (const float4*)&W3[k0*128];
            float4* dst = (float4*)sW;
#pragma unroll
            for (int q=0;q<2;++q) dst[q*256+tid] = src[q*256+tid];
        }
        // stage ef chunk transposed: this thread fills column `tid` for 16 k's
        {
            int kg = k0 >> 2;
#pragma unroll
            for (int q=0;q<4;++q){
                float4 x = pa[kg+q], y = pb[kg+q];
                sE[(q*4+0)*264 + tid] = x.x*y.x;
                sE[(q*4+1)*264 + tid] = x.y*y.y;
                sE[(q*4+2)*264 + tid] = x.z*y.z;
                sE[(q*4+3)*264 + tid] = x.w*y.w;
            }
        }
        __syncthreads();
#pragma unroll 8
        for (int kk=0;kk<KC;++kk){
            float4 ea = *(const float4*)&sE[kk*264 + e0];
            float4 eb = *(const float4*)&sE[kk*264 + e0 + 4];
            float4 wA = *(const float4*)&sW[kk*128 + jA];
            float4 wB = *(const float4*)&sW[kk*128 + jB];
            float4 wC = *(const float4*)&sW[kk*128 + jC];
            float4 wD = *(const float4*)&sW[kk*128 + jD];
            float ev0=ea.x, ev1=ea.y, ev2=ea.z, ev3=ea.w;
            float ev4=eb.x, ev5=eb.y, ev6=eb.z, ev7=eb.w;
#define ROW(i, ev) \
            acc[i][0]+=ev*wA.x;  acc[i][1]+=ev*wA.y;  acc[i][2]+=ev*wA.z;  acc[i][3]+=ev*wA.w; \
            acc[i][4]+=ev*wB.x;  acc[i][5]+=ev*wB.y;  acc[i][6]+=ev*wB.z;  acc[i][7]+=ev*wB.w; \
            acc[i][8]+=ev*wC.x;  acc[i][9]+=ev*wC.y;  acc[i][10]+=ev*wC.z; acc[i][11]+=ev*wC.w; \
            acc[i][12]+=ev*wD.x; acc[i][13]+=ev*wD.y; acc[i][14]+=ev*wD.z; acc[i][15]+=ev*wD.w;
            ROW(0,ev0) ROW(1,ev1) ROW(2,ev2) ROW(3,ev3)
            ROW(4,ev4) ROW(5,ev5) ROW(6,ev6) ROW(7,ev7)
#undef ROW
        }
    }
    float b4v = b4[0];
#pragma unroll
    for (int i=0;i<8;++i){
        float p = fmaxf(acc[i][0]+b3A.x,0.f)*w4A.x
                + fmaxf(acc[i][1]+b3A.y,0.f)*w4A.y
                + fmaxf(acc[i][2]+b3A.z,0.f)*w4A.z
                + fmaxf(acc[i][3]+b3A.w,0.f)*w4A.w
                + fmaxf(acc[i][4]+b3B.x,0.f)*w4B.x
                + fmaxf(acc[i][5]+b3B.y,0.f)*w4B.y
                + fmaxf(acc[i][6]+b3B.z,0.f)*w4B.z
                + fmaxf(acc[i][7]+b3B.w,0.f)*w4B.w
                + fmaxf(acc[i][8]+b3C.x,0.f)*w4C.x
                + fmaxf(acc[i][9]+b3C.y,0.f)*w4C.y
                + fmaxf(acc[i][10]+b3C.z,0.f)*w4C.z
                + fmaxf(acc[i][11]+b3C.w,0.f)*w4C.w
                + fmaxf(acc[i][12]+b3D.x,0.f)*w4D.x
                + fmaxf(acc[i][13]+b3D.y,0.f)*w4D.y
                + fmaxf(acc[i][14]+b3D.z,0.f)*w4D.z
                + fmaxf(acc[i][15]+b3D.w,0.f)*w4D.w;
        p += __shfl_xor(p,1);
        p += __shfl_xor(p,2);
        p += __shfl_xor(p,4);
        if (tx==0) sc[bid*256 + e0 + i] = p + b4v;
    }
}

// ---------------- SSM recurrence (reads tag+sc directly)
__global__ __launch_bounds__(256) void k_ssm2(
    const int* __restrict__ ei, const int* __restrict__ tag,
    const float* __restrict__ sc,
    const float* __restrict__ W_in, const float* __restrict__ conv_w,
    const float* __restrict__ conv_b, const float* __restrict__ dt_bias,
    const float* __restrict__ A_log, const float* __restrict__ D_skip,
    const float* __restrict__ W_out, float* __restrict__ out)
{
    __shared__ float scw[132], scb[33], swin[35];
    int tid = threadIdx.x;
    if (tid < 132) scw[tid] = conv_w[tid];
    if (tid < 33)  scb[tid] = conv_b[tid];
    if (tid < 35)  swin[tid] = W_in[tid];
    __syncthreads();

    int e = blockIdx.x*256 + tid;              // < E
    int a = ei[7*2*Ee + e], b = ei[7*2*Ee + Ee + e];
    int cell = a*Nn + b;
    float x[8];
#pragma unroll
    for (int t=0;t<8;++t){
        int tg = tag[t*NNc + cell];
        x[t] = (tg > 0) ? sc[tg-1] : 0.f;
    }

    float A    = -expf(A_log[0]);
    float dtb  = dt_bias[0];
    float dsk  = D_skip[0];
    float wout = W_out[0];
    float win_z = swin[0], win_dt = swin[34];

    float ssm[16];
#pragma unroll
    for (int q=0;q<16;++q) ssm[q]=0.f;
    float h0=0.f,h1=0.f,h2v=0.f;
    float y=0.f;
    for (int t=0;t<8;++t){
        float xt = x[t];
        float act[33];
#pragma unroll
        for (int c=0;c<33;++c){
            float s = h0*scw[c*4+0] + h1*scw[c*4+1] + h2v*scw[c*4+2] + xt*scw[c*4+3];
            float pre = swin[1+c]*s + scb[c];
            act[c] = pre / (1.f + expf(-pre));
        }
        float x_ = act[0];
        float dtr = xt*win_dt + dtb;
        float dt  = (dtr > 20.f) ? dtr : log1pf(expf(dtr));
        float dA  = expf(dt*A);
        float dx  = dt*x_;
        float yv = 0.f;
#pragma unroll
        for (int q=0;q<16;++q){
            ssm[q] = ssm[q]*dA + dx*act[1+q];
            yv += ssm[q]*act[17+q];
        }
        yv += dsk*x_;
        float z = xt*win_z;
        yv *= z / (1.f + expf(-z));
        y = yv;
        h0=h1; h1=h2v; h2v=xt;
    }
    out[cell] = y*wout;
}

extern "C" void kernel_launch(void* const* d_in, const int* in_sizes, int n_in,
                              void* d_out, int out_size, void* d_ws, size_t ws_size,
                              hipStream_t stream)
{
    const int*   ei    = (const int*)d_in[0];
    const float* ew    = (const float*)d_in[1];
    const float* feats = (const float*)d_in[2];
    const float* noise = (const float*)d_in[3];
    const float* Wp1=(const float*)d_in[4];  const float* bp1=(const float*)d_in[5];
    const float* Wp2=(const float*)d_in[6];  const float* bp2=(const float*)d_in[7];
    const float* W1 =(const float*)d_in[8];  const float* b1 =(const float*)d_in[9];
    const float* W2 =(const float*)d_in[10]; const float* b2 =(const float*)d_in[11];
    const float* W3 =(const float*)d_in[12]; const float* b3 =(const float*)d_in[13];
    const float* w4 =(const float*)d_in[14]; const float* b4 =(const float*)d_in[15];
    const float* W_in  =(const float*)d_in[16]; const float* conv_w=(const float*)d_in[17];
    const float* conv_b=(const float*)d_in[18]; const float* dt_bias=(const float*)d_in[19];
    const float* A_log =(const float*)d_in[20]; const float* D_skip=(const float*)d_in[21];
    const float* W_out =(const float*)d_in[22];

    float* out = (float*)d_out;
    float* ws  = (float*)d_ws;
    float* hh    = ws;                      // T*N*128  = 524288
    float* agg   = hh    + 524288;          // 524288
    float* h2    = agg   + 524288;          // 524288
    float* sc    = h2    + 524288;          // T*E      = 131072
    int*   cnt   = (int*)(sc + 131072);     // T*N      = 4096   (contiguous with tag)
    int*   tag   = cnt + TNr;               // T*N*N    = 2097152
    int*   bucket= tag + 2097152;           // T*N*CAP  = 524288

    hipMemsetAsync(out, 0, (size_t)NNc*4, stream);
    hipMemsetAsync(cnt, 0, (size_t)(TNr + 2097152)*4, stream);   // cnt + tag in one blit

    k_histtag <<<TE/256, 256, 0, stream>>>(ei, cnt, bucket, tag);
    k_fp1     <<<TNr/16, 256, 0, stream>>>(feats, noise, Wp1, bp1, Wp2, bp2, W1, b1, hh);
    k_scatter2<<<TNr, 128, 0, stream>>>(ei, ew, hh, cnt, bucket, agg);
    k_wle2    <<<TNr/16, 256, 0, stream>>>(agg, W2, b2, h2);
    k_edge7   <<<TE/256, 256, 0, stream>>>(ei, h2, W3, b3, w4, b4, sc);
    k_ssm2    <<<Ee/256, 256, 0, stream>>>(ei, tag, sc, W_in, conv_w, conv_b,
                                           dt_bias, A_log, D_skip, W_out, out);
}

// Round 10
// 167.183 us; speedup vs baseline: 4.7911x; 1.0047x over previous
//
#include <hip/hip_runtime.h>
#include <math.h>

#define Nn 512
#define Tt 8
#define Ee 16384
#define NNc (Nn*Nn)          // 262144
#define TNr (Tt*Nn)          // 4096
#define TE  (Tt*Ee)          // 131072
#define CAP 128              // bucket capacity per (t,dst); Poisson(32) => overflow ~1e-35

// ---------------- fused feat_proj + WLE layer1
__global__ __launch_bounds__(256) void k_fp1(
    const float* __restrict__ feats, const float* __restrict__ noise,
    const float* __restrict__ Wp1, const float* __restrict__ bp1,
    const float* __restrict__ Wp2, const float* __restrict__ bp2,
    const float* __restrict__ W1, const float* __restrict__ b1,
    float* __restrict__ hh)
{
    __shared__ float sfeat[16][128];
    __shared__ float sh1[16][256];
    __shared__ float semb[16][80];
    int tid = threadIdx.x;
    int r0 = blockIdx.x * 16;
#pragma unroll
    for (int k = 0; k < 8; ++k) {
        int lin = k*256 + tid;
        sfeat[lin>>7][lin&127] = feats[(size_t)r0*128 + lin];
    }
    {
        int r = tid>>4, k = tid&15;
        semb[r][64+k] = noise[(size_t)(r0+r)*16 + k];
    }
    __syncthreads();
    {
        int j = tid;
        float acc[16];
#pragma unroll
        for (int r=0;r<16;++r) acc[r]=0.f;
        for (int i=0;i<128;i+=4) {
            float w0=Wp1[(i+0)*256+j], w1=Wp1[(i+1)*256+j];
            float w2=Wp1[(i+2)*256+j], w3=Wp1[(i+3)*256+j];
#pragma unroll
            for (int r=0;r<16;++r) {
                float4 f = *(const float4*)&sfeat[r][i];
                acc[r] += f.x*w0 + f.y*w1 + f.z*w2 + f.w*w3;
            }
        }
        float b = bp1[j];
#pragma unroll
        for (int r=0;r<16;++r) sh1[r][j] = fmaxf(acc[r]+b, 0.f);
    }
    __syncthreads();
    {
        int jo = tid & 63;
        int rr = tid >> 6;
        float b2v = bp2[jo];
        for (int rg=0; rg<4; ++rg) {
            int r = rg*4 + rr;
            float a2 = 0.f;
            for (int i=0;i<256;i+=4) {
                float4 f = *(const float4*)&sh1[r][i];
                a2 += f.x*Wp2[(i+0)*64+jo] + f.y*Wp2[(i+1)*64+jo]
                    + f.z*Wp2[(i+2)*64+jo] + f.w*Wp2[(i+3)*64+jo];
            }
            semb[r][jo] = fmaxf(a2+b2v, 0.f);
        }
    }
    __syncthreads();
    {
        int j = tid & 127;
        int rb = (tid>>7)*8;
        float acc[8];
#pragma unroll
        for (int r=0;r<8;++r) acc[r]=0.f;
        for (int i=0;i<80;i+=4) {
            float w0=W1[(i+0)*128+j], w1=W1[(i+1)*128+j];
            float w2=W1[(i+2)*128+j], w3=W1[(i+3)*128+j];
#pragma unroll
            for (int r=0;r<8;++r) {
                float4 f = *(const float4*)&semb[rb+r][i];
                acc[r] += f.x*w0 + f.y*w1 + f.z*w2 + f.w*w3;
            }
        }
        float b = b1[j];
#pragma unroll
        for (int r=0;r<8;++r) hh[(size_t)(r0+rb+r)*128 + j] = fmaxf(acc[r]+b, 0.f);
    }
}

// ---------------- one edge pass: bucket-CSR build + last-write-wins tag
__global__ __launch_bounds__(256) void k_histtag(
    const int* __restrict__ ei, int* __restrict__ cnt,
    int* __restrict__ bucket, int* __restrict__ tag)
{
    int g = blockIdx.x*256 + threadIdx.x;       // < T*E
    int t = g>>14, e = g&(Ee-1);
    int a = ei[t*2*Ee + e];                     // dst
    int b = ei[t*2*Ee + Ee + e];                // src
    int cell = t*Nn + a;
    int pos = atomicAdd(&cnt[cell], 1);
    if (pos < CAP) bucket[cell*CAP + pos] = e;
    atomicMax(&tag[t*NNc + a*Nn + b], g+1);
}

// ---------------- fused: x = hh[dst] + sum ew*hh[src]; h2 = relu(x @ W2 + b2)
__global__ __launch_bounds__(128) void k_sw(
    const int* __restrict__ ei, const float* __restrict__ ew,
    const float* __restrict__ hh, const int* __restrict__ cnt,
    const int* __restrict__ bucket,
    const float* __restrict__ W2, const float* __restrict__ b2,
    float* __restrict__ h2)
{
    __shared__ float sx[128];
    int bid = blockIdx.x;            // < T*Nn
    int t = bid >> 9;
    int ch = threadIdx.x;
    int n = cnt[bid]; n = n < CAP ? n : CAP;
    const int* __restrict__ bk = &bucket[(size_t)bid*CAP];
    const int* __restrict__ eis = &ei[t*2*Ee + Ee];
    const float* __restrict__ ewt = &ew[t*Ee];
    const float* __restrict__ hht = &hh[(size_t)t*Nn*128];
    float acc = hh[(size_t)bid*128 + ch];
    int i = 0;
    for (; i+1 < n; i += 2){
        int e0 = bk[i], e1 = bk[i+1];
        int s0 = eis[e0], s1 = eis[e1];
        float w0 = ewt[e0], w1 = ewt[e1];
        acc += w0*hht[(size_t)s0*128 + ch] + w1*hht[(size_t)s1*128 + ch];
    }
    if (i < n){
        int e0 = bk[i];
        acc += ewt[e0]*hht[(size_t)eis[e0]*128 + ch];
    }
    sx[ch] = acc;
    __syncthreads();
    // GEMV: h2[ch] = relu(b2[ch] + sum_i sx[i]*W2[i][ch])  (W2 rows coalesced, L1-hot)
    float s = 0.f;
    for (int i2=0; i2<128; i2+=4){
        float4 x = *(const float4*)&sx[i2];      // uniform -> broadcast
        s += x.x*W2[(i2+0)*128+ch] + x.y*W2[(i2+1)*128+ch]
           + x.z*W2[(i2+2)*128+ch] + x.w*W2[(i2+3)*128+ch];
    }
    h2[(size_t)bid*128 + ch] = fmaxf(s + b2[ch], 0.f);
}

// ---------------- edge scores, 8e x 16j per thread, KC=16, async-staged:
// prologue-load chunk 0 to regs; loop: barrier -> regs->LDS -> barrier ->
// issue c+1 global loads -> compute c. Loads fly across the compute phase.
#define KC 16
__global__ __launch_bounds__(256) void k_edge8(
    const int* __restrict__ ei, const float* __restrict__ h2,
    const float* __restrict__ W3, const float* __restrict__ b3,
    const float* __restrict__ w4, const float* __restrict__ b4,
    float* __restrict__ sc)
{
    __shared__ float sE[KC*264];      // 16896 B
    __shared__ float sW[KC*128];      // 8192 B
    int tid = threadIdx.x;
    int bid = blockIdx.x;             // < TE/256 = 512
    int tb  = bid >> 6;               // timestep (64 blocks per t)
    int ein = (bid & 63)*256 + tid;   // this thread's staged edge
    int a = ei[tb*2*Ee + ein];
    int b = ei[tb*2*Ee + Ee + ein];
    const float4* __restrict__ pa = (const float4*)&h2[((size_t)(tb*Nn+a))*128];
    const float4* __restrict__ pb = (const float4*)&h2[((size_t)(tb*Nn+b))*128];
    const float4* __restrict__ pw = (const float4*)W3;

    int tx = tid & 7, ty = tid >> 3;  // tx: j-groups, ty: e-groups
    int e0 = ty*8;
    int jA = tx*4, jB = 32+tx*4, jC = 64+tx*4, jD = 96+tx*4;
    float4 b3A = *(const float4*)&b3[jA];
    float4 b3B = *(const float4*)&b3[jB];
    float4 b3C = *(const float4*)&b3[jC];
    float4 b3D = *(const float4*)&b3[jD];
    float4 w4A = *(const float4*)&w4[jA];
    float4 w4B = *(const float4*)&w4[jB];
    float4 w4C = *(const float4*)&w4[jC];
    float4 w4D = *(const float4*)&w4[jD];

    float acc[8][16];
#pragma unroll
    for (int i=0;i<8;++i)
#pragma unroll
        for (int j=0;j<16;++j) acc[i][j]=0.f;

    // staged registers for one chunk
    float4 rw0, rw1, ra0, ra1, ra2, ra3, rb0, rb1, rb2, rb3;
#define LOADC(c) { \
        int kq = (c)*512; /* float4 offset of chunk in W3 */ \
        rw0 = pw[kq + tid]; rw1 = pw[kq + 256 + tid]; \
        int kg = (c)*4; \
        ra0 = pa[kg]; ra1 = pa[kg+1]; ra2 = pa[kg+2]; ra3 = pa[kg+3]; \
        rb0 = pb[kg]; rb1 = pb[kg+1]; rb2 = pb[kg+2]; rb3 = pb[kg+3]; }

    LOADC(0)
    for (int c=0;c<8;++c){
        __syncthreads();              // previous chunk's readers done
        // write staged regs to LDS
        ((float4*)sW)[tid]     = rw0;
        ((float4*)sW)[256+tid] = rw1;
        {
            float4 x, y;
#define PUTE(q, X, Y) x=X; y=Y; \
            sE[((q)*4+0)*264 + tid] = x.x*y.x; \
            sE[((q)*4+1)*264 + tid] = x.y*y.y; \
            sE[((q)*4+2)*264 + tid] = x.z*y.z; \
            sE[((q)*4+3)*264 + tid] = x.w*y.w;
            PUTE(0, ra0, rb0) PUTE(1, ra1, rb1) PUTE(2, ra2, rb2) PUTE(3, ra3, rb3)
#undef PUTE
        }
        __syncthreads();              // LDS ready
        if (c < 7) LOADC(c+1)         // issue next-chunk loads; used after next barrier
#pragma unroll 8
        for (int kk=0;kk<KC;++kk){
            float4 ea = *(const float4*)&sE[kk*264 + e0];
            float4 eb = *(const float4*)&sE[kk*264 + e0 + 4];
            float4 wA = *(const float4*)&sW[kk*128 + jA];
            float4 wB = *(const float4*)&sW[kk*128 + jB];
            float4 wC = *(const float4*)&sW[kk*128 + jC];
            float4 wD = *(const float4*)&sW[kk*128 + jD];
            float ev0=ea.x, ev1=ea.y, ev2=ea.z, ev3=ea.w;
            float ev4=eb.x, ev5=eb.y, ev6=eb.z, ev7=eb.w;
#define ROW(i, ev) \
            acc[i][0]+=ev*wA.x;  acc[i][1]+=ev*wA.y;  acc[i][2]+=ev*wA.z;  acc[i][3]+=ev*wA.w; \
            acc[i][4]+=ev*wB.x;  acc[i][5]+=ev*wB.y;  acc[i][6]+=ev*wB.z;  acc[i][7]+=ev*wB.w; \
            acc[i][8]+=ev*wC.x;  acc[i][9]+=ev*wC.y;  acc[i][10]+=ev*wC.z; acc[i][11]+=ev*wC.w; \
            acc[i][12]+=ev*wD.x; acc[i][13]+=ev*wD.y; acc[i][14]+=ev*wD.z; acc[i][15]+=ev*wD.w;
            ROW(0,ev0) ROW(1,ev1) ROW(2,ev2) ROW(3,ev3)
            ROW(4,ev4) ROW(5,ev5) ROW(6,ev6) ROW(7,ev7)
#undef ROW
        }
    }
#undef LOADC
    float b4v = b4[0];
#pragma unroll
    for (int i=0;i<8;++i){
        float p = fmaxf(acc[i][0]+b3A.x,0.f)*w4A.x
                + fmaxf(acc[i][1]+b3A.y,0.f)*w4A.y
                + fmaxf(acc[i][2]+b3A.z,0.f)*w4A.z
                + fmaxf(acc[i][3]+b3A.w,0.f)*w4A.w
                + fmaxf(acc[i][4]+b3B.x,0.f)*w4B.x
                + fmaxf(acc[i][5]+b3B.y,0.f)*w4B.y
                + fmaxf(acc[i][6]+b3B.z,0.f)*w4B.z
                + fmaxf(acc[i][7]+b3B.w,0.f)*w4B.w
                + fmaxf(acc[i][8]+b3C.x,0.f)*w4C.x
                + fmaxf(acc[i][9]+b3C.y,0.f)*w4C.y
                + fmaxf(acc[i][10]+b3C.z,0.f)*w4C.z
                + fmaxf(acc[i][11]+b3C.w,0.f)*w4C.w
                + fmaxf(acc[i][12]+b3D.x,0.f)*w4D.x
                + fmaxf(acc[i][13]+b3D.y,0.f)*w4D.y
                + fmaxf(acc[i][14]+b3D.z,0.f)*w4D.z
                + fmaxf(acc[i][15]+b3D.w,0.f)*w4D.w;
        p += __shfl_xor(p,1);
        p += __shfl_xor(p,2);
        p += __shfl_xor(p,4);
        if (tx==0) sc[bid*256 + e0 + i] = p + b4v;
    }
}

// ---------------- SSM recurrence (reads tag+sc directly)
__global__ __launch_bounds__(256) void k_ssm2(
    const int* __restrict__ ei, const int* __restrict__ tag,
    const float* __restrict__ sc,
    const float* __restrict__ W_in, const float* __restrict__ conv_w,
    const float* __restrict__ conv_b, const float* __restrict__ dt_bias,
    const float* __restrict__ A_log, const float* __restrict__ D_skip,
    const float* __restrict__ W_out, float* __restrict__ out)
{
    __shared__ float scw[132], scb[33], swin[35];
    int tid = threadIdx.x;
    if (tid < 132) scw[tid] = conv_w[tid];
    if (tid < 33)  scb[tid] = conv_b[tid];
    if (tid < 35)  swin[tid] = W_in[tid];
    __syncthreads();

    int e = blockIdx.x*256 + tid;              // < E
    int a = ei[7*2*Ee + e], b = ei[7*2*Ee + Ee + e];
    int cell = a*Nn + b;
    float x[8];
#pragma unroll
    for (int t=0;t<8;++t){
        int tg = tag[t*NNc + cell];
        x[t] = (tg > 0) ? sc[tg-1] : 0.f;
    }

    float A    = -expf(A_log[0]);
    float dtb  = dt_bias[0];
    float dsk  = D_skip[0];
    float wout = W_out[0];
    float win_z = swin[0], win_dt = swin[34];

    float ssm[16];
#pragma unroll
    for (int q=0;q<16;++q) ssm[q]=0.f;
    float h0=0.f,h1=0.f,h2v=0.f;
    float y=0.f;
    for (int t=0;t<8;++t){
        float xt = x[t];
        float act[33];
#pragma unroll
        for (int c=0;c<33;++c){
            float s = h0*scw[c*4+0] + h1*scw[c*4+1] + h2v*scw[c*4+2] + xt*scw[c*4+3];
            float pre = swin[1+c]*s + scb[c];
            act[c] = pre / (1.f + expf(-pre));
        }
        float x_ = act[0];
        float dtr = xt*win_dt + dtb;
        float dt  = (dtr > 20.f) ? dtr : log1pf(expf(dtr));
        float dA  = expf(dt*A);
        float dx  = dt*x_;
        float yv = 0.f;
#pragma unroll
        for (int q=0;q<16;++q){
            ssm[q] = ssm[q]*dA + dx*act[1+q];
            yv += ssm[q]*act[17+q];
        }
        yv += dsk*x_;
        float z = xt*win_z;
        yv *= z / (1.f + expf(-z));
        y = yv;
        h0=h1; h1=h2v; h2v=xt;
    }
    out[cell] = y*wout;
}

extern "C" void kernel_launch(void* const* d_in, const int* in_sizes, int n_in,
                              void* d_out, int out_size, void* d_ws, size_t ws_size,
                              hipStream_t stream)
{
    const int*   ei    = (const int*)d_in[0];
    const float* ew    = (const float*)d_in[1];
    const float* feats = (const float*)d_in[2];
    const float* noise = (const float*)d_in[3];
    const float* Wp1=(const float*)d_in[4];  const float* bp1=(const float*)d_in[5];
    const float* Wp2=(const float*)d_in[6];  const float* bp2=(const float*)d_in[7];
    const float* W1 =(const float*)d_in[8];  const float* b1 =(const float*)d_in[9];
    const float* W2 =(const float*)d_in[10]; const float* b2 =(const float*)d_in[11];
    const float* W3 =(const float*)d_in[12]; const float* b3 =(const float*)d_in[13];
    const float* w4 =(const float*)d_in[14]; const float* b4 =(const float*)d_in[15];
    const float* W_in  =(const float*)d_in[16]; const float* conv_w=(const float*)d_in[17];
    const float* conv_b=(const float*)d_in[18]; const float* dt_bias=(const float*)d_in[19];
    const float* A_log =(const float*)d_in[20]; const float* D_skip=(const float*)d_in[21];
    const float* W_out =(const float*)d_in[22];

    float* out = (float*)d_out;
    float* ws  = (float*)d_ws;
    float* hh    = ws;                      // T*N*128  = 524288
    float* h2    = hh    + 524288;          // 524288
    float* sc    = h2    + 524288;          // T*E      = 131072
    int*   cnt   = (int*)(sc + 131072);     // T*N      = 4096   (contiguous with tag)
    int*   tag   = cnt + TNr;               // T*N*N    = 2097152
    int*   bucket= tag + 2097152;           // T*N*CAP  = 524288

    hipMemsetAsync(out, 0, (size_t)NNc*4, stream);
    hipMemsetAsync(cnt, 0, (size_t)(TNr + 2097152)*4, stream);   // cnt + tag in one blit

    k_histtag <<<TE/256, 256, 0, stream>>>(ei, cnt, bucket, tag);
    k_fp1     <<<TNr/16, 256, 0, stream>>>(feats, noise, Wp1, bp1, Wp2, bp2, W1, b1, hh);
    k_sw      <<<TNr, 128, 0, stream>>>(ei, ew, hh, cnt, bucket, W2, b2, h2);
    k_edge8   <<<TE/256, 256, 0, stream>>>(ei, h2, W3, b3, w4, b4, sc);
    k_ssm2    <<<Ee/256, 256, 0, stream>>>(ei, tag, sc, W_in, conv_w, conv_b,
                                           dt_bias, A_log, D_skip, W_out, out);
}

// Round 11
// 135.121 us; speedup vs baseline: 5.9280x; 1.2373x over previous
//
#include <hip/hip_runtime.h>
#include <math.h>

#define Nn 512
#define Tt 8
#define Ee 16384
#define NNc (Nn*Nn)          // 262144
#define TNr (Tt*Nn)          // 4096
#define TE  (Tt*Ee)          // 131072
#define CAP 128              // bucket capacity per (t,dst); Poisson(32) => overflow ~1e-35

typedef __bf16 bf16x8 __attribute__((ext_vector_type(8)));
typedef float  f32x4  __attribute__((ext_vector_type(4)));
union BU { uint4 q; bf16x8 v; };

// RNE fp32 -> bf16 hi/lo split, packing two elements into one u32 each.
__device__ __forceinline__ void dec2(float x0, float x1, unsigned &hi, unsigned &lo){
    unsigned u0 = __float_as_uint(x0), u1 = __float_as_uint(x1);
    unsigned t0 = u0 + 0x7FFFu + ((u0>>16)&1u);
    unsigned t1 = u1 + 0x7FFFu + ((u1>>16)&1u);
    hi = (t0>>16) | (t1 & 0xFFFF0000u);
    float h0 = __uint_as_float(t0 & 0xFFFF0000u);
    float h1 = __uint_as_float(t1 & 0xFFFF0000u);
    float l0 = x0 - h0, l1 = x1 - h1;
    unsigned v0 = __float_as_uint(l0), v1 = __float_as_uint(l1);
    unsigned s0 = v0 + 0x7FFFu + ((v0>>16)&1u);
    unsigned s1 = v1 + 0x7FFFu + ((v1>>16)&1u);
    lo = (s0>>16) | (s1 & 0xFFFF0000u);
}

// ---------------- fused feat_proj + WLE layer1
__global__ __launch_bounds__(256) void k_fp1(
    const float* __restrict__ feats, const float* __restrict__ noise,
    const float* __restrict__ Wp1, const float* __restrict__ bp1,
    const float* __restrict__ Wp2, const float* __restrict__ bp2,
    const float* __restrict__ W1, const float* __restrict__ b1,
    float* __restrict__ hh)
{
    __shared__ float sfeat[16][128];
    __shared__ float sh1[16][256];
    __shared__ float semb[16][80];
    int tid = threadIdx.x;
    int r0 = blockIdx.x * 16;
#pragma unroll
    for (int k = 0; k < 8; ++k) {
        int lin = k*256 + tid;
        sfeat[lin>>7][lin&127] = feats[(size_t)r0*128 + lin];
    }
    {
        int r = tid>>4, k = tid&15;
        semb[r][64+k] = noise[(size_t)(r0+r)*16 + k];
    }
    __syncthreads();
    {
        int j = tid;
        float acc[16];
#pragma unroll
        for (int r=0;r<16;++r) acc[r]=0.f;
        for (int i=0;i<128;i+=4) {
            float w0=Wp1[(i+0)*256+j], w1=Wp1[(i+1)*256+j];
            float w2=Wp1[(i+2)*256+j], w3=Wp1[(i+3)*256+j];
#pragma unroll
            for (int r=0;r<16;++r) {
                float4 f = *(const float4*)&sfeat[r][i];
                acc[r] += f.x*w0 + f.y*w1 + f.z*w2 + f.w*w3;
            }
        }
        float b = bp1[j];
#pragma unroll
        for (int r=0;r<16;++r) sh1[r][j] = fmaxf(acc[r]+b, 0.f);
    }
    __syncthreads();
    {
        int jo = tid & 63;
        int rr = tid >> 6;
        float b2v = bp2[jo];
        for (int rg=0; rg<4; ++rg) {
            int r = rg*4 + rr;
            float a2 = 0.f;
            for (int i=0;i<256;i+=4) {
                float4 f = *(const float4*)&sh1[r][i];
                a2 += f.x*Wp2[(i+0)*64+jo] + f.y*Wp2[(i+1)*64+jo]
                    + f.z*Wp2[(i+2)*64+jo] + f.w*Wp2[(i+3)*64+jo];
            }
            semb[r][jo] = fmaxf(a2+b2v, 0.f);
        }
    }
    __syncthreads();
    {
        int j = tid & 127;
        int rb = (tid>>7)*8;
        float acc[8];
#pragma unroll
        for (int r=0;r<8;++r) acc[r]=0.f;
        for (int i=0;i<80;i+=4) {
            float w0=W1[(i+0)*128+j], w1=W1[(i+1)*128+j];
            float w2=W1[(i+2)*128+j], w3=W1[(i+3)*128+j];
#pragma unroll
            for (int r=0;r<8;++r) {
                float4 f = *(const float4*)&semb[rb+r][i];
                acc[r] += f.x*w0 + f.y*w1 + f.z*w2 + f.w*w3;
            }
        }
        float b = b1[j];
#pragma unroll
        for (int r=0;r<8;++r) hh[(size_t)(r0+rb+r)*128 + j] = fmaxf(acc[r]+b, 0.f);
    }
}

// ---------------- one edge pass: bucket-CSR build + last-write-wins tag
__global__ __launch_bounds__(256) void k_histtag(
    const int* __restrict__ ei, int* __restrict__ cnt,
    int* __restrict__ bucket, int* __restrict__ tag)
{
    int g = blockIdx.x*256 + threadIdx.x;       // < T*E
    int t = g>>14, e = g&(Ee-1);
    int a = ei[t*2*Ee + e];                     // dst
    int b = ei[t*2*Ee + Ee + e];                // src
    int cell = t*Nn + a;
    int pos = atomicAdd(&cnt[cell], 1);
    if (pos < CAP) bucket[cell*CAP + pos] = e;
    atomicMax(&tag[t*NNc + a*Nn + b], g+1);
}

// ---------------- fused: x = hh[dst] + sum ew*hh[src]; h2 = relu(x @ W2 + b2)
__global__ __launch_bounds__(128) void k_sw(
    const int* __restrict__ ei, const float* __restrict__ ew,
    const float* __restrict__ hh, const int* __restrict__ cnt,
    const int* __restrict__ bucket,
    const float* __restrict__ W2, const float* __restrict__ b2,
    float* __restrict__ h2)
{
    __shared__ float sx[128];
    int bid = blockIdx.x;            // < T*Nn
    int t = bid >> 9;
    int ch = threadIdx.x;
    int n = cnt[bid]; n = n < CAP ? n : CAP;
    const int* __restrict__ bk = &bucket[(size_t)bid*CAP];
    const int* __restrict__ eis = &ei[t*2*Ee + Ee];
    const float* __restrict__ ewt = &ew[t*Ee];
    const float* __restrict__ hht = &hh[(size_t)t*Nn*128];
    float acc = hh[(size_t)bid*128 + ch];
    int i = 0;
    for (; i+1 < n; i += 2){
        int e0 = bk[i], e1 = bk[i+1];
        int s0 = eis[e0], s1 = eis[e1];
        float w0 = ewt[e0], w1 = ewt[e1];
        acc += w0*hht[(size_t)s0*128 + ch] + w1*hht[(size_t)s1*128 + ch];
    }
    if (i < n){
        int e0 = bk[i];
        acc += ewt[e0]*hht[(size_t)eis[e0]*128 + ch];
    }
    sx[ch] = acc;
    __syncthreads();
    float s = 0.f;
    for (int i2=0; i2<128; i2+=4){
        float4 x = *(const float4*)&sx[i2];
        s += x.x*W2[(i2+0)*128+ch] + x.y*W2[(i2+1)*128+ch]
           + x.z*W2[(i2+2)*128+ch] + x.w*W2[(i2+3)*128+ch];
    }
    h2[(size_t)bid*128 + ch] = fmaxf(s + b2[ch], 0.f);
}

// ---------------- prep: split W3 into bf16 hi/lo, pre-swizzled into MFMA B-fragment order.
// ushort index: ((kt*8+jt)*64 + lane)*8 + i  <=>  W3[kt*32 + (lane>>4)*8 + i][jt*16 + (lane&15)]
__global__ __launch_bounds__(256) void k_w3p(
    const float* __restrict__ W3, unsigned short* __restrict__ w3h,
    unsigned short* __restrict__ w3l)
{
    int tid = blockIdx.x*256 + threadIdx.x;   // < 16384
    int i    = tid & 7;
    int lane = (tid>>3) & 63;
    int jt   = (tid>>9) & 7;
    int kt   = tid>>12;
    int k = kt*32 + (lane>>4)*8 + i;
    int j = jt*16 + (lane&15);
    float x = W3[k*128 + j];
    unsigned u = __float_as_uint(x);
    unsigned t = u + 0x7FFFu + ((u>>16)&1u);
    w3h[tid] = (unsigned short)(t>>16);
    float hf = __uint_as_float(t & 0xFFFF0000u);
    float lf = x - hf;
    unsigned v = __float_as_uint(lf);
    unsigned s = v + 0x7FFFu + ((v>>16)&1u);
    w3l[tid] = (unsigned short)(s>>16);
}

// ---------------- edge scores via split-bf16 MFMA:
// D = Ah*Bh + Ah*Bl + Al*Bh in fp32 accum (error ~2^-17 rel, >>100x inside threshold).
// Block: 256 thr = 4 waves; wave owns 32 edges x 128 j, K=128. W3h/W3l fragments in LDS
// (staged once, NO barriers in main loop). A/B packed with the same k-map, so any k-map
// error is a summation permutation (exact); C/D map is the HW-verified one.
__global__ __launch_bounds__(256) void k_edge9(
    const int* __restrict__ ei, const float* __restrict__ h2,
    const uint4* __restrict__ w3h, const uint4* __restrict__ w3l,
    const float* __restrict__ b3, const float* __restrict__ w4,
    const float* __restrict__ b4, float* __restrict__ sc)
{
    __shared__ uint4 sBh[2048];   // 32 KB
    __shared__ uint4 sBl[2048];   // 32 KB
    int tid = threadIdx.x;
    int bid = blockIdx.x;                  // < 1024
#pragma unroll
    for (int q=0;q<8;++q){
        sBh[q*256+tid] = w3h[q*256+tid];
        sBl[q*256+tid] = w3l[q*256+tid];
    }
    int tb  = bid >> 7;                    // timestep (128 blocks/t)
    int e0b = (bid & 127) * 128;
    int w   = tid >> 6, lane = tid & 63;
    int e0w = e0b + w*32;
    int r16 = lane & 15, g4 = lane >> 4;

    const int* __restrict__ eit = &ei[tb*2*Ee];
    int a0 = eit[e0w + r16],      s0 = eit[Ee + e0w + r16];
    int a1 = eit[e0w + 16 + r16], s1 = eit[Ee + e0w + 16 + r16];
    const float* __restrict__ pa0 = &h2[(size_t)(tb*Nn+a0)*128];
    const float* __restrict__ pb0 = &h2[(size_t)(tb*Nn+s0)*128];
    const float* __restrict__ pa1 = &h2[(size_t)(tb*Nn+a1)*128];
    const float* __restrict__ pb1 = &h2[(size_t)(tb*Nn+s1)*128];

    float b3v[8], w4v[8];
#pragma unroll
    for (int jt=0;jt<8;++jt){ b3v[jt] = b3[jt*16 + r16]; w4v[jt] = w4[jt*16 + r16]; }

    f32x4 acc0[8], acc1[8];
#pragma unroll
    for (int jt=0;jt<8;++jt){
        acc0[jt] = (f32x4){0.f,0.f,0.f,0.f};
        acc1[jt] = (f32x4){0.f,0.f,0.f,0.f};
    }
    __syncthreads();

#pragma unroll
    for (int kt=0;kt<4;++kt){
        int k0 = kt*32 + g4*8;
        BU Ah0, Al0, Ah1, Al1;
        {
            float4 xa = *(const float4*)&pa0[k0], ya = *(const float4*)&pa0[k0+4];
            float4 xb = *(const float4*)&pb0[k0], yb = *(const float4*)&pb0[k0+4];
            uint4 hq, lq;
            dec2(xa.x*xb.x, xa.y*xb.y, hq.x, lq.x);
            dec2(xa.z*xb.z, xa.w*xb.w, hq.y, lq.y);
            dec2(ya.x*yb.x, ya.y*yb.y, hq.z, lq.z);
            dec2(ya.z*yb.z, ya.w*yb.w, hq.w, lq.w);
            Ah0.q = hq; Al0.q = lq;
        }
        {
            float4 xa = *(const float4*)&pa1[k0], ya = *(const float4*)&pa1[k0+4];
            float4 xb = *(const float4*)&pb1[k0], yb = *(const float4*)&pb1[k0+4];
            uint4 hq, lq;
            dec2(xa.x*xb.x, xa.y*xb.y, hq.x, lq.x);
            dec2(xa.z*xb.z, xa.w*xb.w, hq.y, lq.y);
            dec2(ya.x*yb.x, ya.y*yb.y, hq.z, lq.z);
            dec2(ya.z*yb.z, ya.w*yb.w, hq.w, lq.w);
            Ah1.q = hq; Al1.q = lq;
        }
#pragma unroll
        for (int jt=0;jt<8;++jt){
            BU Bh, Bl;
            Bh.q = sBh[(kt*8+jt)*64 + lane];
            Bl.q = sBl[(kt*8+jt)*64 + lane];
            acc0[jt] = __builtin_amdgcn_mfma_f32_16x16x32_bf16(Ah0.v, Bh.v, acc0[jt], 0,0,0);
            acc0[jt] = __builtin_amdgcn_mfma_f32_16x16x32_bf16(Ah0.v, Bl.v, acc0[jt], 0,0,0);
            acc0[jt] = __builtin_amdgcn_mfma_f32_16x16x32_bf16(Al0.v, Bh.v, acc0[jt], 0,0,0);
            acc1[jt] = __builtin_amdgcn_mfma_f32_16x16x32_bf16(Ah1.v, Bh.v, acc1[jt], 0,0,0);
            acc1[jt] = __builtin_amdgcn_mfma_f32_16x16x32_bf16(Ah1.v, Bl.v, acc1[jt], 0,0,0);
            acc1[jt] = __builtin_amdgcn_mfma_f32_16x16x32_bf16(Al1.v, Bh.v, acc1[jt], 0,0,0);
        }
    }

    // epilogue: per C/D map (col=lane&15, row=(lane>>4)*4+reg), reduce over j (cols+tiles)
    float b4v = b4[0];
#pragma unroll
    for (int r=0;r<4;++r){
        float p0 = 0.f, p1 = 0.f;
#pragma unroll
        for (int jt=0;jt<8;++jt){
            p0 += fmaxf(acc0[jt][r] + b3v[jt], 0.f) * w4v[jt];
            p1 += fmaxf(acc1[jt][r] + b3v[jt], 0.f) * w4v[jt];
        }
        p0 += __shfl_xor(p0,1); p0 += __shfl_xor(p0,2);
        p0 += __shfl_xor(p0,4); p0 += __shfl_xor(p0,8);
        p1 += __shfl_xor(p1,1); p1 += __shfl_xor(p1,2);
        p1 += __shfl_xor(p1,4); p1 += __shfl_xor(p1,8);
        if (r16 == 0){
            sc[(size_t)tb*Ee + e0w + g4*4 + r]      = p0 + b4v;
            sc[(size_t)tb*Ee + e0w + 16 + g4*4 + r] = p1 + b4v;
        }
    }
}

// ---------------- SSM recurrence (reads tag+sc directly)
__global__ __launch_bounds__(256) void k_ssm2(
    const int* __restrict__ ei, const int* __restrict__ tag,
    const float* __restrict__ sc,
    const float* __restrict__ W_in, const float* __restrict__ conv_w,
    const float* __restrict__ conv_b, const float* __restrict__ dt_bias,
    const float* __restrict__ A_log, const float* __restrict__ D_skip,
    const float* __restrict__ W_out, float* __restrict__ out)
{
    __shared__ float scw[132], scb[33], swin[35];
    int tid = threadIdx.x;
    if (tid < 132) scw[tid] = conv_w[tid];
    if (tid < 33)  scb[tid] = conv_b[tid];
    if (tid < 35)  swin[tid] = W_in[tid];
    __syncthreads();

    int e = blockIdx.x*256 + tid;              // < E
    int a = ei[7*2*Ee + e], b = ei[7*2*Ee + Ee + e];
    int cell = a*Nn + b;
    float x[8];
#pragma unroll
    for (int t=0;t<8;++t){
        int tg = tag[t*NNc + cell];
        x[t] = (tg > 0) ? sc[tg-1] : 0.f;
    }

    float A    = -expf(A_log[0]);
    float dtb  = dt_bias[0];
    float dsk  = D_skip[0];
    float wout = W_out[0];
    float win_z = swin[0], win_dt = swin[34];

    float ssm[16];
#pragma unroll
    for (int q=0;q<16;++q) ssm[q]=0.f;
    float h0=0.f,h1=0.f,h2v=0.f;
    float y=0.f;
    for (int t=0;t<8;++t){
        float xt = x[t];
        float act[33];
#pragma unroll
        for (int c=0;c<33;++c){
            float s = h0*scw[c*4+0] + h1*scw[c*4+1] + h2v*scw[c*4+2] + xt*scw[c*4+3];
            float pre = swin[1+c]*s + scb[c];
            act[c] = pre / (1.f + expf(-pre));
        }
        float x_ = act[0];
        float dtr = xt*win_dt + dtb;
        float dt  = (dtr > 20.f) ? dtr : log1pf(expf(dtr));
        float dA  = expf(dt*A);
        float dx  = dt*x_;
        float yv = 0.f;
#pragma unroll
        for (int q=0;q<16;++q){
            ssm[q] = ssm[q]*dA + dx*act[1+q];
            yv += ssm[q]*act[17+q];
        }
        yv += dsk*x_;
        float z = xt*win_z;
        yv *= z / (1.f + expf(-z));
        y = yv;
        h0=h1; h1=h2v; h2v=xt;
    }
    out[cell] = y*wout;
}

extern "C" void kernel_launch(void* const* d_in, const int* in_sizes, int n_in,
                              void* d_out, int out_size, void* d_ws, size_t ws_size,
                              hipStream_t stream)
{
    const int*   ei    = (const int*)d_in[0];
    const float* ew    = (const float*)d_in[1];
    const float* feats = (const float*)d_in[2];
    const float* noise = (const float*)d_in[3];
    const float* Wp1=(const float*)d_in[4];  const float* bp1=(const float*)d_in[5];
    const float* Wp2=(const float*)d_in[6];  const float* bp2=(const float*)d_in[7];
    const float* W1 =(const float*)d_in[8];  const float* b1 =(const float*)d_in[9];
    const float* W2 =(const float*)d_in[10]; const float* b2 =(const float*)d_in[11];
    const float* W3 =(const float*)d_in[12]; const float* b3 =(const float*)d_in[13];
    const float* w4 =(const float*)d_in[14]; const float* b4 =(const float*)d_in[15];
    const float* W_in  =(const float*)d_in[16]; const float* conv_w=(const float*)d_in[17];
    const float* conv_b=(const float*)d_in[18]; const float* dt_bias=(const float*)d_in[19];
    const float* A_log =(const float*)d_in[20]; const float* D_skip=(const float*)d_in[21];
    const float* W_out =(const float*)d_in[22];

    float* out = (float*)d_out;
    float* ws  = (float*)d_ws;
    float* hh    = ws;                      // T*N*128  = 524288
    float* h2    = hh    + 524288;          // 524288
    float* sc    = h2    + 524288;          // T*E      = 131072
    int*   cnt   = (int*)(sc + 131072);     // T*N      = 4096   (contiguous with tag)
    int*   tag   = cnt + TNr;               // T*N*N    = 2097152
    int*   bucket= tag + 2097152;           // T*N*CAP  = 524288
    unsigned short* w3h = (unsigned short*)(bucket + 524288);   // 16384 ushort = 8192 B... (32KB total)
    unsigned short* w3l = w3h + 16384;      // 16384 ushort

    hipMemsetAsync(out, 0, (size_t)NNc*4, stream);
    hipMemsetAsync(cnt, 0, (size_t)(TNr + 2097152)*4, stream);   // cnt + tag in one blit

    k_w3p     <<<64, 256, 0, stream>>>(W3, w3h, w3l);
    k_histtag <<<TE/256, 256, 0, stream>>>(ei, cnt, bucket, tag);
    k_fp1     <<<TNr/16, 256, 0, stream>>>(feats, noise, Wp1, bp1, Wp2, bp2, W1, b1, hh);
    k_sw      <<<TNr, 128, 0, stream>>>(ei, ew, hh, cnt, bucket, W2, b2, h2);
    k_edge9   <<<1024, 256, 0, stream>>>(ei, h2, (const uint4*)w3h, (const uint4*)w3l,
                                         b3, w4, b4, sc);
    k_ssm2    <<<Ee/256, 256, 0, stream>>>(ei, tag, sc, W_in, conv_w, conv_b,
                                           dt_bias, A_log, D_skip, W_out, out);
}

// Round 12
// 130.089 us; speedup vs baseline: 6.1573x; 1.0387x over previous
//
#include <hip/hip_runtime.h>
#include <math.h>

#define Nn 512
#define Tt 8
#define Ee 16384
#define NNc (Nn*Nn)          // 262144
#define TNr (Tt*Nn)          // 4096
#define TE  (Tt*Ee)          // 131072
#define CAP 128              // bucket capacity per (t,dst); Poisson(32) => overflow ~1e-35

typedef __bf16 bf16x8 __attribute__((ext_vector_type(8)));
typedef float  f32x4  __attribute__((ext_vector_type(4)));
union BU { uint4 q; bf16x8 v; };

// RNE fp32 -> bf16 hi/lo split, packing two elements into one u32 each.
__device__ __forceinline__ void dec2(float x0, float x1, unsigned &hi, unsigned &lo){
    unsigned u0 = __float_as_uint(x0), u1 = __float_as_uint(x1);
    unsigned t0 = u0 + 0x7FFFu + ((u0>>16)&1u);
    unsigned t1 = u1 + 0x7FFFu + ((u1>>16)&1u);
    hi = (t0>>16) | (t1 & 0xFFFF0000u);
    float h0 = __uint_as_float(t0 & 0xFFFF0000u);
    float h1 = __uint_as_float(t1 & 0xFFFF0000u);
    float l0 = x0 - h0, l1 = x1 - h1;
    unsigned v0 = __float_as_uint(l0), v1 = __float_as_uint(l1);
    unsigned s0 = v0 + 0x7FFFu + ((v0>>16)&1u);
    unsigned s1 = v1 + 0x7FFFu + ((v1>>16)&1u);
    lo = (s0>>16) | (s1 & 0xFFFF0000u);
}

// ---------------- targeted zero: replaces BOTH memsets.
// tag only needs zeroing at entries k_ssm2 probes: the t7 edge cells x 8 planes.
// Stale values elsewhere are never read; probed entries are re-zeroed then
// re-maxed with identical values every call -> deterministic across replays.
__global__ __launch_bounds__(256) void k_zero(
    const int* __restrict__ ei, int* __restrict__ cnt, int* __restrict__ tag,
    float4* __restrict__ out4)
{
    int e = blockIdx.x*256 + threadIdx.x;   // < Ee
    int a = ei[7*2*Ee + e], b = ei[7*2*Ee + Ee + e];
    int cell = a*Nn + b;
#pragma unroll
    for (int t=0;t<8;++t) tag[t*NNc + cell] = 0;
    if (e < TNr) cnt[e] = 0;
    float4 z = {0.f,0.f,0.f,0.f};
#pragma unroll
    for (int q=0;q<4;++q) out4[q*16384 + e] = z;   // 65536 float4 = full out
}

// ---------------- fused feat_proj + WLE layer1
__global__ __launch_bounds__(256) void k_fp1(
    const float* __restrict__ feats, const float* __restrict__ noise,
    const float* __restrict__ Wp1, const float* __restrict__ bp1,
    const float* __restrict__ Wp2, const float* __restrict__ bp2,
    const float* __restrict__ W1, const float* __restrict__ b1,
    float* __restrict__ hh)
{
    __shared__ float sfeat[16][128];
    __shared__ float sh1[16][256];
    __shared__ float semb[16][80];
    int tid = threadIdx.x;
    int r0 = blockIdx.x * 16;
#pragma unroll
    for (int k = 0; k < 8; ++k) {
        int lin = k*256 + tid;
        sfeat[lin>>7][lin&127] = feats[(size_t)r0*128 + lin];
    }
    {
        int r = tid>>4, k = tid&15;
        semb[r][64+k] = noise[(size_t)(r0+r)*16 + k];
    }
    __syncthreads();
    {
        int j = tid;
        float acc[16];
#pragma unroll
        for (int r=0;r<16;++r) acc[r]=0.f;
        for (int i=0;i<128;i+=4) {
            float w0=Wp1[(i+0)*256+j], w1=Wp1[(i+1)*256+j];
            float w2=Wp1[(i+2)*256+j], w3=Wp1[(i+3)*256+j];
#pragma unroll
            for (int r=0;r<16;++r) {
                float4 f = *(const float4*)&sfeat[r][i];
                acc[r] += f.x*w0 + f.y*w1 + f.z*w2 + f.w*w3;
            }
        }
        float b = bp1[j];
#pragma unroll
        for (int r=0;r<16;++r) sh1[r][j] = fmaxf(acc[r]+b, 0.f);
    }
    __syncthreads();
    {
        int jo = tid & 63;
        int rr = tid >> 6;
        float b2v = bp2[jo];
        for (int rg=0; rg<4; ++rg) {
            int r = rg*4 + rr;
            float a2 = 0.f;
            for (int i=0;i<256;i+=4) {
                float4 f = *(const float4*)&sh1[r][i];
                a2 += f.x*Wp2[(i+0)*64+jo] + f.y*Wp2[(i+1)*64+jo]
                    + f.z*Wp2[(i+2)*64+jo] + f.w*Wp2[(i+3)*64+jo];
            }
            semb[r][jo] = fmaxf(a2+b2v, 0.f);
        }
    }
    __syncthreads();
    {
        int j = tid & 127;
        int rb = (tid>>7)*8;
        float acc[8];
#pragma unroll
        for (int r=0;r<8;++r) acc[r]=0.f;
        for (int i=0;i<80;i+=4) {
            float w0=W1[(i+0)*128+j], w1=W1[(i+1)*128+j];
            float w2=W1[(i+2)*128+j], w3=W1[(i+3)*128+j];
#pragma unroll
            for (int r=0;r<8;++r) {
                float4 f = *(const float4*)&semb[rb+r][i];
                acc[r] += f.x*w0 + f.y*w1 + f.z*w2 + f.w*w3;
            }
        }
        float b = b1[j];
#pragma unroll
        for (int r=0;r<8;++r) hh[(size_t)(r0+rb+r)*128 + j] = fmaxf(acc[r]+b, 0.f);
    }
}

// ---------------- one edge pass: bucket-CSR build + last-write-wins tag
__global__ __launch_bounds__(256) void k_histtag(
    const int* __restrict__ ei, int* __restrict__ cnt,
    int* __restrict__ bucket, int* __restrict__ tag)
{
    int g = blockIdx.x*256 + threadIdx.x;       // < T*E
    int t = g>>14, e = g&(Ee-1);
    int a = ei[t*2*Ee + e];                     // dst
    int b = ei[t*2*Ee + Ee + e];                // src
    int cell = t*Nn + a;
    int pos = atomicAdd(&cnt[cell], 1);
    if (pos < CAP) bucket[cell*CAP + pos] = e;
    atomicMax(&tag[t*NNc + a*Nn + b], g+1);
}

// ---------------- fused: x = hh[dst] + sum ew*hh[src]; h2 = relu(x @ W2 + b2)
__global__ __launch_bounds__(128) void k_sw(
    const int* __restrict__ ei, const float* __restrict__ ew,
    const float* __restrict__ hh, const int* __restrict__ cnt,
    const int* __restrict__ bucket,
    const float* __restrict__ W2, const float* __restrict__ b2,
    float* __restrict__ h2)
{
    __shared__ float sx[128];
    int bid = blockIdx.x;            // < T*Nn
    int t = bid >> 9;
    int ch = threadIdx.x;
    int n = cnt[bid]; n = n < CAP ? n : CAP;
    const int* __restrict__ bk = &bucket[(size_t)bid*CAP];
    const int* __restrict__ eis = &ei[t*2*Ee + Ee];
    const float* __restrict__ ewt = &ew[t*Ee];
    const float* __restrict__ hht = &hh[(size_t)t*Nn*128];
    float acc = hh[(size_t)bid*128 + ch];
    int i = 0;
    for (; i+1 < n; i += 2){
        int e0 = bk[i], e1 = bk[i+1];
        int s0 = eis[e0], s1 = eis[e1];
        float w0 = ewt[e0], w1 = ewt[e1];
        acc += w0*hht[(size_t)s0*128 + ch] + w1*hht[(size_t)s1*128 + ch];
    }
    if (i < n){
        int e0 = bk[i];
        acc += ewt[e0]*hht[(size_t)eis[e0]*128 + ch];
    }
    sx[ch] = acc;
    __syncthreads();
    float s = 0.f;
    for (int i2=0; i2<128; i2+=4){
        float4 x = *(const float4*)&sx[i2];
        s += x.x*W2[(i2+0)*128+ch] + x.y*W2[(i2+1)*128+ch]
           + x.z*W2[(i2+2)*128+ch] + x.w*W2[(i2+3)*128+ch];
    }
    h2[(size_t)bid*128 + ch] = fmaxf(s + b2[ch], 0.f);
}

// ---------------- prep: split W3 into bf16 hi/lo, pre-swizzled into MFMA B-fragment order.
__global__ __launch_bounds__(256) void k_w3p(
    const float* __restrict__ W3, unsigned short* __restrict__ w3h,
    unsigned short* __restrict__ w3l)
{
    int tid = blockIdx.x*256 + threadIdx.x;   // < 16384
    int i    = tid & 7;
    int lane = (tid>>3) & 63;
    int jt   = (tid>>9) & 7;
    int kt   = tid>>12;
    int k = kt*32 + (lane>>4)*8 + i;
    int j = jt*16 + (lane&15);
    float x = W3[k*128 + j];
    unsigned u = __float_as_uint(x);
    unsigned t = u + 0x7FFFu + ((u>>16)&1u);
    w3h[tid] = (unsigned short)(t>>16);
    float hf = __uint_as_float(t & 0xFFFF0000u);
    float lf = x - hf;
    unsigned v = __float_as_uint(lf);
    unsigned s = v + 0x7FFFu + ((v>>16)&1u);
    w3l[tid] = (unsigned short)(s>>16);
}

// ---------------- edge scores via split-bf16 MFMA (D = AhBh + AhBl + AlBh, fp32 accum)
__global__ __launch_bounds__(256) void k_edge9(
    const int* __restrict__ ei, const float* __restrict__ h2,
    const uint4* __restrict__ w3h, const uint4* __restrict__ w3l,
    const float* __restrict__ b3, const float* __restrict__ w4,
    const float* __restrict__ b4, float* __restrict__ sc)
{
    __shared__ uint4 sBh[2048];   // 32 KB
    __shared__ uint4 sBl[2048];   // 32 KB
    int tid = threadIdx.x;
    int bid = blockIdx.x;                  // < 1024
#pragma unroll
    for (int q=0;q<8;++q){
        sBh[q*256+tid] = w3h[q*256+tid];
        sBl[q*256+tid] = w3l[q*256+tid];
    }
    int tb  = bid >> 7;                    // timestep (128 blocks/t)
    int e0b = (bid & 127) * 128;
    int w   = tid >> 6, lane = tid & 63;
    int e0w = e0b + w*32;
    int r16 = lane & 15, g4 = lane >> 4;

    const int* __restrict__ eit = &ei[tb*2*Ee];
    int a0 = eit[e0w + r16],      s0 = eit[Ee + e0w + r16];
    int a1 = eit[e0w + 16 + r16], s1 = eit[Ee + e0w + 16 + r16];
    const float* __restrict__ pa0 = &h2[(size_t)(tb*Nn+a0)*128];
    const float* __restrict__ pb0 = &h2[(size_t)(tb*Nn+s0)*128];
    const float* __restrict__ pa1 = &h2[(size_t)(tb*Nn+a1)*128];
    const float* __restrict__ pb1 = &h2[(size_t)(tb*Nn+s1)*128];

    float b3v[8], w4v[8];
#pragma unroll
    for (int jt=0;jt<8;++jt){ b3v[jt] = b3[jt*16 + r16]; w4v[jt] = w4[jt*16 + r16]; }

    f32x4 acc0[8], acc1[8];
#pragma unroll
    for (int jt=0;jt<8;++jt){
        acc0[jt] = (f32x4){0.f,0.f,0.f,0.f};
        acc1[jt] = (f32x4){0.f,0.f,0.f,0.f};
    }
    __syncthreads();

#pragma unroll
    for (int kt=0;kt<4;++kt){
        int k0 = kt*32 + g4*8;
        BU Ah0, Al0, Ah1, Al1;
        {
            float4 xa = *(const float4*)&pa0[k0], ya = *(const float4*)&pa0[k0+4];
            float4 xb = *(const float4*)&pb0[k0], yb = *(const float4*)&pb0[k0+4];
            uint4 hq, lq;
            dec2(xa.x*xb.x, xa.y*xb.y, hq.x, lq.x);
            dec2(xa.z*xb.z, xa.w*xb.w, hq.y, lq.y);
            dec2(ya.x*yb.x, ya.y*yb.y, hq.z, lq.z);
            dec2(ya.z*yb.z, ya.w*yb.w, hq.w, lq.w);
            Ah0.q = hq; Al0.q = lq;
        }
        {
            float4 xa = *(const float4*)&pa1[k0], ya = *(const float4*)&pa1[k0+4];
            float4 xb = *(const float4*)&pb1[k0], yb = *(const float4*)&pb1[k0+4];
            uint4 hq, lq;
            dec2(xa.x*xb.x, xa.y*xb.y, hq.x, lq.x);
            dec2(xa.z*xb.z, xa.w*xb.w, hq.y, lq.y);
            dec2(ya.x*yb.x, ya.y*yb.y, hq.z, lq.z);
            dec2(ya.z*yb.z, ya.w*yb.w, hq.w, lq.w);
            Ah1.q = hq; Al1.q = lq;
        }
#pragma unroll
        for (int jt=0;jt<8;++jt){
            BU Bh, Bl;
            Bh.q = sBh[(kt*8+jt)*64 + lane];
            Bl.q = sBl[(kt*8+jt)*64 + lane];
            acc0[jt] = __builtin_amdgcn_mfma_f32_16x16x32_bf16(Ah0.v, Bh.v, acc0[jt], 0,0,0);
            acc0[jt] = __builtin_amdgcn_mfma_f32_16x16x32_bf16(Ah0.v, Bl.v, acc0[jt], 0,0,0);
            acc0[jt] = __builtin_amdgcn_mfma_f32_16x16x32_bf16(Al0.v, Bh.v, acc0[jt], 0,0,0);
            acc1[jt] = __builtin_amdgcn_mfma_f32_16x16x32_bf16(Ah1.v, Bh.v, acc1[jt], 0,0,0);
            acc1[jt] = __builtin_amdgcn_mfma_f32_16x16x32_bf16(Ah1.v, Bl.v, acc1[jt], 0,0,0);
            acc1[jt] = __builtin_amdgcn_mfma_f32_16x16x32_bf16(Al1.v, Bh.v, acc1[jt], 0,0,0);
        }
    }

    float b4v = b4[0];
#pragma unroll
    for (int r=0;r<4;++r){
        float p0 = 0.f, p1 = 0.f;
#pragma unroll
        for (int jt=0;jt<8;++jt){
            p0 += fmaxf(acc0[jt][r] + b3v[jt], 0.f) * w4v[jt];
            p1 += fmaxf(acc1[jt][r] + b3v[jt], 0.f) * w4v[jt];
        }
        p0 += __shfl_xor(p0,1); p0 += __shfl_xor(p0,2);
        p0 += __shfl_xor(p0,4); p0 += __shfl_xor(p0,8);
        p1 += __shfl_xor(p1,1); p1 += __shfl_xor(p1,2);
        p1 += __shfl_xor(p1,4); p1 += __shfl_xor(p1,8);
        if (r16 == 0){
            sc[(size_t)tb*Ee + e0w + g4*4 + r]      = p0 + b4v;
            sc[(size_t)tb*Ee + e0w + 16 + g4*4 + r] = p1 + b4v;
        }
    }
}

// ---------------- SSM recurrence (reads tag+sc directly)
__global__ __launch_bounds__(256) void k_ssm2(
    const int* __restrict__ ei, const int* __restrict__ tag,
    const float* __restrict__ sc,
    const float* __restrict__ W_in, const float* __restrict__ conv_w,
    const float* __restrict__ conv_b, const float* __restrict__ dt_bias,
    const float* __restrict__ A_log, const float* __restrict__ D_skip,
    const float* __restrict__ W_out, float* __restrict__ out)
{
    __shared__ float scw[132], scb[33], swin[35];
    int tid = threadIdx.x;
    if (tid < 132) scw[tid] = conv_w[tid];
    if (tid < 33)  scb[tid] = conv_b[tid];
    if (tid < 35)  swin[tid] = W_in[tid];
    __syncthreads();

    int e = blockIdx.x*256 + tid;              // < E
    int a = ei[7*2*Ee + e], b = ei[7*2*Ee + Ee + e];
    int cell = a*Nn + b;
    float x[8];
#pragma unroll
    for (int t=0;t<8;++t){
        int tg = tag[t*NNc + cell];
        x[t] = (tg > 0) ? sc[tg-1] : 0.f;
    }

    float A    = -expf(A_log[0]);
    float dtb  = dt_bias[0];
    float dsk  = D_skip[0];
    float wout = W_out[0];
    float win_z = swin[0], win_dt = swin[34];

    float ssm[16];
#pragma unroll
    for (int q=0;q<16;++q) ssm[q]=0.f;
    float h0=0.f,h1=0.f,h2v=0.f;
    float y=0.f;
    for (int t=0;t<8;++t){
        float xt = x[t];
        float act[33];
#pragma unroll
        for (int c=0;c<33;++c){
            float s = h0*scw[c*4+0] + h1*scw[c*4+1] + h2v*scw[c*4+2] + xt*scw[c*4+3];
            float pre = swin[1+c]*s + scb[c];
            act[c] = pre / (1.f + expf(-pre));
        }
        float x_ = act[0];
        float dtr = xt*win_dt + dtb;
        float dt  = (dtr > 20.f) ? dtr : log1pf(expf(dtr));
        float dA  = expf(dt*A);
        float dx  = dt*x_;
        float yv = 0.f;
#pragma unroll
        for (int q=0;q<16;++q){
            ssm[q] = ssm[q]*dA + dx*act[1+q];
            yv += ssm[q]*act[17+q];
        }
        yv += dsk*x_;
        float z = xt*win_z;
        yv *= z / (1.f + expf(-z));
        y = yv;
        h0=h1; h1=h2v; h2v=xt;
    }
    out[cell] = y*wout;
}

extern "C" void kernel_launch(void* const* d_in, const int* in_sizes, int n_in,
                              void* d_out, int out_size, void* d_ws, size_t ws_size,
                              hipStream_t stream)
{
    const int*   ei    = (const int*)d_in[0];
    const float* ew    = (const float*)d_in[1];
    const float* feats = (const float*)d_in[2];
    const float* noise = (const float*)d_in[3];
    const float* Wp1=(const float*)d_in[4];  const float* bp1=(const float*)d_in[5];
    const float* Wp2=(const float*)d_in[6];  const float* bp2=(const float*)d_in[7];
    const float* W1 =(const float*)d_in[8];  const float* b1 =(const float*)d_in[9];
    const float* W2 =(const float*)d_in[10]; const float* b2 =(const float*)d_in[11];
    const float* W3 =(const float*)d_in[12]; const float* b3 =(const float*)d_in[13];
    const float* w4 =(const float*)d_in[14]; const float* b4 =(const float*)d_in[15];
    const float* W_in  =(const float*)d_in[16]; const float* conv_w=(const float*)d_in[17];
    const float* conv_b=(const float*)d_in[18]; const float* dt_bias=(const float*)d_in[19];
    const float* A_log =(const float*)d_in[20]; const float* D_skip=(const float*)d_in[21];
    const float* W_out =(const float*)d_in[22];

    float* out = (float*)d_out;
    float* ws  = (float*)d_ws;
    float* hh    = ws;                      // T*N*128  = 524288
    float* h2    = hh    + 524288;          // 524288
    float* sc    = h2    + 524288;          // T*E      = 131072
    int*   cnt   = (int*)(sc + 131072);     // T*N      = 4096
    int*   tag   = cnt + TNr;               // T*N*N    = 2097152
    int*   bucket= tag + 2097152;           // T*N*CAP  = 524288
    unsigned short* w3h = (unsigned short*)(bucket + 524288);   // 16384
    unsigned short* w3l = w3h + 16384;      // 16384

    k_zero    <<<Ee/256, 256, 0, stream>>>(ei, cnt, tag, (float4*)out);
    k_w3p     <<<64, 256, 0, stream>>>(W3, w3h, w3l);
    k_histtag <<<TE/256, 256, 0, stream>>>(ei, cnt, bucket, tag);
    k_fp1     <<<TNr/16, 256, 0, stream>>>(feats, noise, Wp1, bp1, Wp2, bp2, W1, b1, hh);
    k_sw      <<<TNr, 128, 0, stream>>>(ei, ew, hh, cnt, bucket, W2, b2, h2);
    k_edge9   <<<1024, 256, 0, stream>>>(ei, h2, (const uint4*)w3h, (const uint4*)w3l,
                                         b3, w4, b4, sc);
    k_ssm2    <<<Ee/256, 256, 0, stream>>>(ei, tag, sc, W_in, conv_w, conv_b,
                                           dt_bias, A_log, D_skip, W_out, out);
}

// Round 13
// 126.446 us; speedup vs baseline: 6.3347x; 1.0288x over previous
//
#include <hip/hip_runtime.h>
#include <math.h>

#define Nn 512
#define Tt 8
#define Ee 16384
#define NNc (Nn*Nn)          // 262144
#define TNr (Tt*Nn)          // 4096
#define TE  (Tt*Ee)          // 131072
#define CAP 128              // bucket capacity per (t,dst); Poisson(32) => overflow ~1e-35

typedef __bf16 bf16x8 __attribute__((ext_vector_type(8)));
typedef float  f32x4  __attribute__((ext_vector_type(4)));
union BU { uint4 q; bf16x8 v; };

// RNE fp32 -> bf16 hi/lo split, packing two elements into one u32 each.
__device__ __forceinline__ void dec2(float x0, float x1, unsigned &hi, unsigned &lo){
    unsigned u0 = __float_as_uint(x0), u1 = __float_as_uint(x1);
    unsigned t0 = u0 + 0x7FFFu + ((u0>>16)&1u);
    unsigned t1 = u1 + 0x7FFFu + ((u1>>16)&1u);
    hi = (t0>>16) | (t1 & 0xFFFF0000u);
    float h0 = __uint_as_float(t0 & 0xFFFF0000u);
    float h1 = __uint_as_float(t1 & 0xFFFF0000u);
    float l0 = x0 - h0, l1 = x1 - h1;
    unsigned v0 = __float_as_uint(l0), v1 = __float_as_uint(l1);
    unsigned s0 = v0 + 0x7FFFu + ((v0>>16)&1u);
    unsigned s1 = v1 + 0x7FFFu + ((v1>>16)&1u);
    lo = (s0>>16) | (s1 & 0xFFFF0000u);
}

// ---------------- prep: targeted zero (tag probed entries, cnt, out) + W3 bf16 hi/lo
// split pre-swizzled into MFMA B-fragment order. 16384 threads.
__global__ __launch_bounds__(256) void k_prep(
    const int* __restrict__ ei, const float* __restrict__ W3,
    unsigned short* __restrict__ w3h, unsigned short* __restrict__ w3l,
    int* __restrict__ cnt, int* __restrict__ tag, float4* __restrict__ out4)
{
    int e = blockIdx.x*256 + threadIdx.x;   // < 16384
    // --- zero the probed tag entries (t7 edge cells x 8 planes), cnt, out
    int a = ei[7*2*Ee + e], b = ei[7*2*Ee + Ee + e];
    int cell = a*Nn + b;
#pragma unroll
    for (int t=0;t<8;++t) tag[t*NNc + cell] = 0;
    if (e < TNr) cnt[e] = 0;
    float4 z = {0.f,0.f,0.f,0.f};
#pragma unroll
    for (int q=0;q<4;++q) out4[q*16384 + e] = z;   // 65536 float4 = full out
    // --- W3 split: element index e <=> ((kt*8+jt)*64 + lane)*8 + i
    int i    = e & 7;
    int lane = (e>>3) & 63;
    int jt   = (e>>9) & 7;
    int kt   = e>>12;
    int k = kt*32 + (lane>>4)*8 + i;
    int j = jt*16 + (lane&15);
    float x = W3[k*128 + j];
    unsigned u = __float_as_uint(x);
    unsigned t = u + 0x7FFFu + ((u>>16)&1u);
    w3h[e] = (unsigned short)(t>>16);
    float hf = __uint_as_float(t & 0xFFFF0000u);
    float lf = x - hf;
    unsigned v = __float_as_uint(lf);
    unsigned s = v + 0x7FFFu + ((v>>16)&1u);
    w3l[e] = (unsigned short)(s>>16);
}

// ---------------- fused feat_proj + WLE layer1
__global__ __launch_bounds__(256) void k_fp1(
    const float* __restrict__ feats, const float* __restrict__ noise,
    const float* __restrict__ Wp1, const float* __restrict__ bp1,
    const float* __restrict__ Wp2, const float* __restrict__ bp2,
    const float* __restrict__ W1, const float* __restrict__ b1,
    float* __restrict__ hh)
{
    __shared__ float sfeat[16][128];
    __shared__ float sh1[16][256];
    __shared__ float semb[16][80];
    int tid = threadIdx.x;
    int r0 = blockIdx.x * 16;
#pragma unroll
    for (int k = 0; k < 8; ++k) {
        int lin = k*256 + tid;
        sfeat[lin>>7][lin&127] = feats[(size_t)r0*128 + lin];
    }
    {
        int r = tid>>4, k = tid&15;
        semb[r][64+k] = noise[(size_t)(r0+r)*16 + k];
    }
    __syncthreads();
    {
        int j = tid;
        float acc[16];
#pragma unroll
        for (int r=0;r<16;++r) acc[r]=0.f;
        for (int i=0;i<128;i+=4) {
            float w0=Wp1[(i+0)*256+j], w1=Wp1[(i+1)*256+j];
            float w2=Wp1[(i+2)*256+j], w3=Wp1[(i+3)*256+j];
#pragma unroll
            for (int r=0;r<16;++r) {
                float4 f = *(const float4*)&sfeat[r][i];
                acc[r] += f.x*w0 + f.y*w1 + f.z*w2 + f.w*w3;
            }
        }
        float b = bp1[j];
#pragma unroll
        for (int r=0;r<16;++r) sh1[r][j] = fmaxf(acc[r]+b, 0.f);
    }
    __syncthreads();
    {
        int jo = tid & 63;
        int rr = tid >> 6;
        float b2v = bp2[jo];
        for (int rg=0; rg<4; ++rg) {
            int r = rg*4 + rr;
            float a2 = 0.f;
            for (int i=0;i<256;i+=4) {
                float4 f = *(const float4*)&sh1[r][i];
                a2 += f.x*Wp2[(i+0)*64+jo] + f.y*Wp2[(i+1)*64+jo]
                    + f.z*Wp2[(i+2)*64+jo] + f.w*Wp2[(i+3)*64+jo];
            }
            semb[r][jo] = fmaxf(a2+b2v, 0.f);
        }
    }
    __syncthreads();
    {
        int j = tid & 127;
        int rb = (tid>>7)*8;
        float acc[8];
#pragma unroll
        for (int r=0;r<8;++r) acc[r]=0.f;
        for (int i=0;i<80;i+=4) {
            float w0=W1[(i+0)*128+j], w1=W1[(i+1)*128+j];
            float w2=W1[(i+2)*128+j], w3=W1[(i+3)*128+j];
#pragma unroll
            for (int r=0;r<8;++r) {
                float4 f = *(const float4*)&semb[rb+r][i];
                acc[r] += f.x*w0 + f.y*w1 + f.z*w2 + f.w*w3;
            }
        }
        float b = b1[j];
#pragma unroll
        for (int r=0;r<8;++r) hh[(size_t)(r0+rb+r)*128 + j] = fmaxf(acc[r]+b, 0.f);
    }
}

// ---------------- one edge pass: bucket-CSR build + last-write-wins tag
__global__ __launch_bounds__(256) void k_histtag(
    const int* __restrict__ ei, int* __restrict__ cnt,
    int* __restrict__ bucket, int* __restrict__ tag)
{
    int g = blockIdx.x*256 + threadIdx.x;       // < T*E
    int t = g>>14, e = g&(Ee-1);
    int a = ei[t*2*Ee + e];                     // dst
    int b = ei[t*2*Ee + Ee + e];                // src
    int cell = t*Nn + a;
    int pos = atomicAdd(&cnt[cell], 1);
    if (pos < CAP) bucket[cell*CAP + pos] = e;
    atomicMax(&tag[t*NNc + a*Nn + b], g+1);
}

// ---------------- fused: x = hh[dst] + sum ew*hh[src]; h2 = relu(x @ W2 + b2)
// 2 dsts per block: second half-block re-reads the same W2 lines -> L1-hot,
// halving the 268MB W2 L2 stream.
__global__ __launch_bounds__(256) void k_sw(
    const int* __restrict__ ei, const float* __restrict__ ew,
    const float* __restrict__ hh, const int* __restrict__ cnt,
    const int* __restrict__ bucket,
    const float* __restrict__ W2, const float* __restrict__ b2,
    float* __restrict__ h2)
{
    __shared__ float sx[2][128];
    int dloc = threadIdx.x >> 7;     // 0/1
    int ch = threadIdx.x & 127;
    int bidd = blockIdx.x*2 + dloc;  // dst cell index < T*Nn
    int t = bidd >> 9;
    int n = cnt[bidd]; n = n < CAP ? n : CAP;
    const int* __restrict__ bk = &bucket[(size_t)bidd*CAP];
    const int* __restrict__ eis = &ei[t*2*Ee + Ee];
    const float* __restrict__ ewt = &ew[t*Ee];
    const float* __restrict__ hht = &hh[(size_t)t*Nn*128];
    float acc = hh[(size_t)bidd*128 + ch];
    int i = 0;
    for (; i+1 < n; i += 2){
        int e0 = bk[i], e1 = bk[i+1];
        int s0 = eis[e0], s1 = eis[e1];
        float w0 = ewt[e0], w1 = ewt[e1];
        acc += w0*hht[(size_t)s0*128 + ch] + w1*hht[(size_t)s1*128 + ch];
    }
    if (i < n){
        int e0 = bk[i];
        acc += ewt[e0]*hht[(size_t)eis[e0]*128 + ch];
    }
    sx[dloc][ch] = acc;
    __syncthreads();
    float s = 0.f;
    for (int i2=0; i2<128; i2+=4){
        float4 x = *(const float4*)&sx[dloc][i2];
        s += x.x*W2[(i2+0)*128+ch] + x.y*W2[(i2+1)*128+ch]
           + x.z*W2[(i2+2)*128+ch] + x.w*W2[(i2+3)*128+ch];
    }
    h2[(size_t)bidd*128 + ch] = fmaxf(s + b2[ch], 0.f);
}

// ---------------- edge scores via split-bf16 MFMA (D = AhBh + AhBl + AlBh, fp32 accum)
// 512 threads = 8 waves, 256 edges/block: halves the W3-fragment staging passes.
__global__ __launch_bounds__(512) void k_edge9(
    const int* __restrict__ ei, const float* __restrict__ h2,
    const uint4* __restrict__ w3h, const uint4* __restrict__ w3l,
    const float* __restrict__ b3, const float* __restrict__ w4,
    const float* __restrict__ b4, float* __restrict__ sc)
{
    __shared__ uint4 sBh[2048];   // 32 KB
    __shared__ uint4 sBl[2048];   // 32 KB
    int tid = threadIdx.x;
    int bid = blockIdx.x;                  // < 512
#pragma unroll
    for (int q=0;q<4;++q){
        sBh[q*512+tid] = w3h[q*512+tid];
        sBl[q*512+tid] = w3l[q*512+tid];
    }
    int tb  = bid >> 6;                    // timestep (64 blocks/t)
    int e0b = (bid & 63) * 256;
    int w   = tid >> 6, lane = tid & 63;
    int e0w = e0b + w*32;
    int r16 = lane & 15, g4 = lane >> 4;

    const int* __restrict__ eit = &ei[tb*2*Ee];
    int a0 = eit[e0w + r16],      s0 = eit[Ee + e0w + r16];
    int a1 = eit[e0w + 16 + r16], s1 = eit[Ee + e0w + 16 + r16];
    const float* __restrict__ pa0 = &h2[(size_t)(tb*Nn+a0)*128];
    const float* __restrict__ pb0 = &h2[(size_t)(tb*Nn+s0)*128];
    const float* __restrict__ pa1 = &h2[(size_t)(tb*Nn+a1)*128];
    const float* __restrict__ pb1 = &h2[(size_t)(tb*Nn+s1)*128];

    float b3v[8], w4v[8];
#pragma unroll
    for (int jt=0;jt<8;++jt){ b3v[jt] = b3[jt*16 + r16]; w4v[jt] = w4[jt*16 + r16]; }

    f32x4 acc0[8], acc1[8];
#pragma unroll
    for (int jt=0;jt<8;++jt){
        acc0[jt] = (f32x4){0.f,0.f,0.f,0.f};
        acc1[jt] = (f32x4){0.f,0.f,0.f,0.f};
    }
    __syncthreads();

#pragma unroll
    for (int kt=0;kt<4;++kt){
        int k0 = kt*32 + g4*8;
        BU Ah0, Al0, Ah1, Al1;
        {
            float4 xa = *(const float4*)&pa0[k0], ya = *(const float4*)&pa0[k0+4];
            float4 xb = *(const float4*)&pb0[k0], yb = *(const float4*)&pb0[k0+4];
            uint4 hq, lq;
            dec2(xa.x*xb.x, xa.y*xb.y, hq.x, lq.x);
            dec2(xa.z*xb.z, xa.w*xb.w, hq.y, lq.y);
            dec2(ya.x*yb.x, ya.y*yb.y, hq.z, lq.z);
            dec2(ya.z*yb.z, ya.w*yb.w, hq.w, lq.w);
            Ah0.q = hq; Al0.q = lq;
        }
        {
            float4 xa = *(const float4*)&pa1[k0], ya = *(const float4*)&pa1[k0+4];
            float4 xb = *(const float4*)&pb1[k0], yb = *(const float4*)&pb1[k0+4];
            uint4 hq, lq;
            dec2(xa.x*xb.x, xa.y*xb.y, hq.x, lq.x);
            dec2(xa.z*xb.z, xa.w*xb.w, hq.y, lq.y);
            dec2(ya.x*yb.x, ya.y*yb.y, hq.z, lq.z);
            dec2(ya.z*yb.z, ya.w*yb.w, hq.w, lq.w);
            Ah1.q = hq; Al1.q = lq;
        }
#pragma unroll
        for (int jt=0;jt<8;++jt){
            BU Bh, Bl;
            Bh.q = sBh[(kt*8+jt)*64 + lane];
            Bl.q = sBl[(kt*8+jt)*64 + lane];
            acc0[jt] = __builtin_amdgcn_mfma_f32_16x16x32_bf16(Ah0.v, Bh.v, acc0[jt], 0,0,0);
            acc0[jt] = __builtin_amdgcn_mfma_f32_16x16x32_bf16(Ah0.v, Bl.v, acc0[jt], 0,0,0);
            acc0[jt] = __builtin_amdgcn_mfma_f32_16x16x32_bf16(Al0.v, Bh.v, acc0[jt], 0,0,0);
            acc1[jt] = __builtin_amdgcn_mfma_f32_16x16x32_bf16(Ah1.v, Bh.v, acc1[jt], 0,0,0);
            acc1[jt] = __builtin_amdgcn_mfma_f32_16x16x32_bf16(Ah1.v, Bl.v, acc1[jt], 0,0,0);
            acc1[jt] = __builtin_amdgcn_mfma_f32_16x16x32_bf16(Al1.v, Bh.v, acc1[jt], 0,0,0);
        }
    }

    float b4v = b4[0];
#pragma unroll
    for (int r=0;r<4;++r){
        float p0 = 0.f, p1 = 0.f;
#pragma unroll
        for (int jt=0;jt<8;++jt){
            p0 += fmaxf(acc0[jt][r] + b3v[jt], 0.f) * w4v[jt];
            p1 += fmaxf(acc1[jt][r] + b3v[jt], 0.f) * w4v[jt];
        }
        p0 += __shfl_xor(p0,1); p0 += __shfl_xor(p0,2);
        p0 += __shfl_xor(p0,4); p0 += __shfl_xor(p0,8);
        p1 += __shfl_xor(p1,1); p1 += __shfl_xor(p1,2);
        p1 += __shfl_xor(p1,4); p1 += __shfl_xor(p1,8);
        if (r16 == 0){
            sc[(size_t)tb*Ee + e0w + g4*4 + r]      = p0 + b4v;
            sc[(size_t)tb*Ee + e0w + 16 + g4*4 + r] = p1 + b4v;
        }
    }
}

// ---------------- SSM recurrence (reads tag+sc directly)
__global__ __launch_bounds__(256) void k_ssm2(
    const int* __restrict__ ei, const int* __restrict__ tag,
    const float* __restrict__ sc,
    const float* __restrict__ W_in, const float* __restrict__ conv_w,
    const float* __restrict__ conv_b, const float* __restrict__ dt_bias,
    const float* __restrict__ A_log, const float* __restrict__ D_skip,
    const float* __restrict__ W_out, float* __restrict__ out)
{
    __shared__ float scw[132], scb[33], swin[35];
    int tid = threadIdx.x;
    if (tid < 132) scw[tid] = conv_w[tid];
    if (tid < 33)  scb[tid] = conv_b[tid];
    if (tid < 35)  swin[tid] = W_in[tid];
    __syncthreads();

    int e = blockIdx.x*256 + tid;              // < E
    int a = ei[7*2*Ee + e], b = ei[7*2*Ee + Ee + e];
    int cell = a*Nn + b;
    float x[8];
#pragma unroll
    for (int t=0;t<8;++t){
        int tg = tag[t*NNc + cell];
        x[t] = (tg > 0) ? sc[tg-1] : 0.f;
    }

    float A    = -expf(A_log[0]);
    float dtb  = dt_bias[0];
    float dsk  = D_skip[0];
    float wout = W_out[0];
    float win_z = swin[0], win_dt = swin[34];

    float ssm[16];
#pragma unroll
    for (int q=0;q<16;++q) ssm[q]=0.f;
    float h0=0.f,h1=0.f,h2v=0.f;
    float y=0.f;
    for (int t=0;t<8;++t){
        float xt = x[t];
        float act[33];
#pragma unroll
        for (int c=0;c<33;++c){
            float s = h0*scw[c*4+0] + h1*scw[c*4+1] + h2v*scw[c*4+2] + xt*scw[c*4+3];
            float pre = swin[1+c]*s + scb[c];
            act[c] = pre / (1.f + expf(-pre));
        }
        float x_ = act[0];
        float dtr = xt*win_dt + dtb;
        float dt  = (dtr > 20.f) ? dtr : log1pf(expf(dtr));
        float dA  = expf(dt*A);
        float dx  = dt*x_;
        float yv = 0.f;
#pragma unroll
        for (int q=0;q<16;++q){
            ssm[q] = ssm[q]*dA + dx*act[1+q];
            yv += ssm[q]*act[17+q];
        }
        yv += dsk*x_;
        float z = xt*win_z;
        yv *= z / (1.f + expf(-z));
        y = yv;
        h0=h1; h1=h2v; h2v=xt;
    }
    out[cell] = y*wout;
}

extern "C" void kernel_launch(void* const* d_in, const int* in_sizes, int n_in,
                              void* d_out, int out_size, void* d_ws, size_t ws_size,
                              hipStream_t stream)
{
    const int*   ei    = (const int*)d_in[0];
    const float* ew    = (const float*)d_in[1];
    const float* feats = (const float*)d_in[2];
    const float* noise = (const float*)d_in[3];
    const float* Wp1=(const float*)d_in[4];  const float* bp1=(const float*)d_in[5];
    const float* Wp2=(const float*)d_in[6];  const float* bp2=(const float*)d_in[7];
    const float* W1 =(const float*)d_in[8];  const float* b1 =(const float*)d_in[9];
    const float* W2 =(const float*)d_in[10]; const float* b2 =(const float*)d_in[11];
    const float* W3 =(const float*)d_in[12]; const float* b3 =(const float*)d_in[13];
    const float* w4 =(const float*)d_in[14]; const float* b4 =(const float*)d_in[15];
    const float* W_in  =(const float*)d_in[16]; const float* conv_w=(const float*)d_in[17];
    const float* conv_b=(const float*)d_in[18]; const float* dt_bias=(const float*)d_in[19];
    const float* A_log =(const float*)d_in[20]; const float* D_skip=(const float*)d_in[21];
    const float* W_out =(const float*)d_in[22];

    float* out = (float*)d_out;
    float* ws  = (float*)d_ws;
    float* hh    = ws;                      // T*N*128  = 524288
    float* h2    = hh    + 524288;          // 524288
    float* sc    = h2    + 524288;          // T*E      = 131072
    int*   cnt   = (int*)(sc + 131072);     // T*N      = 4096
    int*   tag   = cnt + TNr;               // T*N*N    = 2097152
    int*   bucket= tag + 2097152;           // T*N*CAP  = 524288
    unsigned short* w3h = (unsigned short*)(bucket + 524288);   // 16384
    unsigned short* w3l = w3h + 16384;      // 16384

    k_prep    <<<Ee/256, 256, 0, stream>>>(ei, W3, w3h, w3l, cnt, tag, (float4*)out);
    k_histtag <<<TE/256, 256, 0, stream>>>(ei, cnt, bucket, tag);
    k_fp1     <<<TNr/16, 256, 0, stream>>>(feats, noise, Wp1, bp1, Wp2, bp2, W1, b1, hh);
    k_sw      <<<TNr/2, 256, 0, stream>>>(ei, ew, hh, cnt, bucket, W2, b2, h2);
    k_edge9   <<<512, 512, 0, stream>>>(ei, h2, (const uint4*)w3h, (const uint4*)w3l,
                                        b3, w4, b4, sc);
    k_ssm2    <<<Ee/256, 256, 0, stream>>>(ei, tag, sc, W_in, conv_w, conv_b,
                                           dt_bias, A_log, D_skip, W_out, out);
}

// Round 14
// 107.242 us; speedup vs baseline: 7.4691x; 1.1791x over previous
//
#include <hip/hip_runtime.h>
#include <math.h>

#define Nn 512
#define Tt 8
#define Ee 16384
#define NNc (Nn*Nn)          // 262144
#define TNr (Tt*Nn)          // 4096
#define TE  (Tt*Ee)          // 131072
#define CAP 128              // bucket capacity per (t,dst); Poisson(32) => overflow ~1e-35

typedef __bf16 bf16x8 __attribute__((ext_vector_type(8)));
typedef float  f32x4  __attribute__((ext_vector_type(4)));
union BU { uint4 q; bf16x8 v; };

// RNE fp32 -> bf16 hi/lo split, packing two elements into one u32 each.
__device__ __forceinline__ void dec2(float x0, float x1, unsigned &hi, unsigned &lo){
    unsigned u0 = __float_as_uint(x0), u1 = __float_as_uint(x1);
    unsigned t0 = u0 + 0x7FFFu + ((u0>>16)&1u);
    unsigned t1 = u1 + 0x7FFFu + ((u1>>16)&1u);
    hi = (t0>>16) | (t1 & 0xFFFF0000u);
    float h0 = __uint_as_float(t0 & 0xFFFF0000u);
    float h1 = __uint_as_float(t1 & 0xFFFF0000u);
    float l0 = x0 - h0, l1 = x1 - h1;
    unsigned v0 = __float_as_uint(l0), v1 = __float_as_uint(l1);
    unsigned s0 = v0 + 0x7FFFu + ((v0>>16)&1u);
    unsigned s1 = v1 + 0x7FFFu + ((v1>>16)&1u);
    lo = (s0>>16) | (s1 & 0xFFFF0000u);
}

// ---------------- merged prep (blocks 0..63) + feat_proj/WLE1 (blocks 64..319)
__global__ __launch_bounds__(256) void k_pf(
    const int* __restrict__ ei, const float* __restrict__ W3,
    unsigned short* __restrict__ w3h, unsigned short* __restrict__ w3l,
    int* __restrict__ cnt, int* __restrict__ tag, float4* __restrict__ out4,
    const float* __restrict__ feats, const float* __restrict__ noise,
    const float* __restrict__ Wp1, const float* __restrict__ bp1,
    const float* __restrict__ Wp2, const float* __restrict__ bp2,
    const float* __restrict__ W1, const float* __restrict__ b1,
    float* __restrict__ hh)
{
    __shared__ float sfeat[16][128];
    __shared__ float sh1[16][256];
    __shared__ float semb[16][80];
    int tid = threadIdx.x;
    if (blockIdx.x < 64){
        // ---- prep: targeted zero + W3 bf16 hi/lo split in MFMA-fragment order
        int e = blockIdx.x*256 + tid;   // < 16384
        int a = ei[7*2*Ee + e], b = ei[7*2*Ee + Ee + e];
        int cell = a*Nn + b;
#pragma unroll
        for (int t=0;t<8;++t) tag[t*NNc + cell] = 0;
        if (e < TNr) cnt[e] = 0;
        float4 z = {0.f,0.f,0.f,0.f};
#pragma unroll
        for (int q=0;q<4;++q) out4[q*16384 + e] = z;
        int i    = e & 7;
        int lane = (e>>3) & 63;
        int jt   = (e>>9) & 7;
        int kt   = e>>12;
        int k = kt*32 + (lane>>4)*8 + i;
        int j = jt*16 + (lane&15);
        float x = W3[k*128 + j];
        unsigned u = __float_as_uint(x);
        unsigned t = u + 0x7FFFu + ((u>>16)&1u);
        w3h[e] = (unsigned short)(t>>16);
        float hf = __uint_as_float(t & 0xFFFF0000u);
        float lf = x - hf;
        unsigned v = __float_as_uint(lf);
        unsigned s = v + 0x7FFFu + ((v>>16)&1u);
        w3l[e] = (unsigned short)(s>>16);
        return;
    }
    // ---- fp1
    int r0 = (blockIdx.x - 64) * 16;
#pragma unroll
    for (int k = 0; k < 8; ++k) {
        int lin = k*256 + tid;
        sfeat[lin>>7][lin&127] = feats[(size_t)r0*128 + lin];
    }
    {
        int r = tid>>4, k = tid&15;
        semb[r][64+k] = noise[(size_t)(r0+r)*16 + k];
    }
    __syncthreads();
    {
        int j = tid;
        float acc[16];
#pragma unroll
        for (int r=0;r<16;++r) acc[r]=0.f;
        for (int i=0;i<128;i+=4) {
            float w0=Wp1[(i+0)*256+j], w1=Wp1[(i+1)*256+j];
            float w2=Wp1[(i+2)*256+j], w3=Wp1[(i+3)*256+j];
#pragma unroll
            for (int r=0;r<16;++r) {
                float4 f = *(const float4*)&sfeat[r][i];
                acc[r] += f.x*w0 + f.y*w1 + f.z*w2 + f.w*w3;
            }
        }
        float b = bp1[j];
#pragma unroll
        for (int r=0;r<16;++r) sh1[r][j] = fmaxf(acc[r]+b, 0.f);
    }
    __syncthreads();
    {
        int jo = tid & 63;
        int rr = tid >> 6;
        float b2v = bp2[jo];
        for (int rg=0; rg<4; ++rg) {
            int r = rg*4 + rr;
            float a2 = 0.f;
            for (int i=0;i<256;i+=4) {
                float4 f = *(const float4*)&sh1[r][i];
                a2 += f.x*Wp2[(i+0)*64+jo] + f.y*Wp2[(i+1)*64+jo]
                    + f.z*Wp2[(i+2)*64+jo] + f.w*Wp2[(i+3)*64+jo];
            }
            semb[r][jo] = fmaxf(a2+b2v, 0.f);
        }
    }
    __syncthreads();
    {
        int j = tid & 127;
        int rb = (tid>>7)*8;
        float acc[8];
#pragma unroll
        for (int r=0;r<8;++r) acc[r]=0.f;
        for (int i=0;i<80;i+=4) {
            float w0=W1[(i+0)*128+j], w1=W1[(i+1)*128+j];
            float w2=W1[(i+2)*128+j], w3=W1[(i+3)*128+j];
#pragma unroll
            for (int r=0;r<8;++r) {
                float4 f = *(const float4*)&semb[rb+r][i];
                acc[r] += f.x*w0 + f.y*w1 + f.z*w2 + f.w*w3;
            }
        }
        float b = b1[j];
#pragma unroll
        for (int r=0;r<8;++r) hh[(size_t)(r0+rb+r)*128 + j] = fmaxf(acc[r]+b, 0.f);
    }
}

// ---------------- edge pass: bucket-CSR with PACKED (src, weight) + last-write-wins tag
__global__ __launch_bounds__(256) void k_histtag(
    const int* __restrict__ ei, const float* __restrict__ ew,
    int* __restrict__ cnt, int2* __restrict__ bucket2, int* __restrict__ tag)
{
    int g = blockIdx.x*256 + threadIdx.x;       // < T*E
    int t = g>>14, e = g&(Ee-1);
    int a = ei[t*2*Ee + e];                     // dst
    int b = ei[t*2*Ee + Ee + e];                // src
    int cell = t*Nn + a;
    int pos = atomicAdd(&cnt[cell], 1);
    if (pos < CAP) bucket2[(size_t)cell*CAP + pos] = make_int2(b, __float_as_int(ew[g]));
    atomicMax(&tag[t*NNc + a*Nn + b], g+1);
}

// ---------------- fused: x = hh[dst] + sum w*hh[src]; h2 = relu(x @ W2 + b2)
// bucket entries carry (src,w) -> 2-level dependency chain only.
__global__ __launch_bounds__(256) void k_sw(
    const float* __restrict__ hh, const int* __restrict__ cnt,
    const int2* __restrict__ bucket2,
    const float* __restrict__ W2, const float* __restrict__ b2,
    float* __restrict__ h2)
{
    __shared__ float sx[2][128];
    int dloc = threadIdx.x >> 7;     // 0/1
    int ch = threadIdx.x & 127;
    int bidd = blockIdx.x*2 + dloc;  // dst cell index < T*Nn
    int t = bidd >> 9;
    int n = cnt[bidd]; n = n < CAP ? n : CAP;
    const int2* __restrict__ bk = &bucket2[(size_t)bidd*CAP];
    const float* __restrict__ hht = &hh[(size_t)t*Nn*128];
    float acc = hh[(size_t)bidd*128 + ch];
    int i = 0;
    for (; i+1 < n; i += 2){
        int2 p0 = bk[i], p1 = bk[i+1];
        acc += __int_as_float(p0.y)*hht[(size_t)p0.x*128 + ch]
             + __int_as_float(p1.y)*hht[(size_t)p1.x*128 + ch];
    }
    if (i < n){
        int2 p = bk[i];
        acc += __int_as_float(p.y)*hht[(size_t)p.x*128 + ch];
    }
    sx[dloc][ch] = acc;
    __syncthreads();
    float s = 0.f;
    for (int i2=0; i2<128; i2+=4){
        float4 x = *(const float4*)&sx[dloc][i2];
        s += x.x*W2[(i2+0)*128+ch] + x.y*W2[(i2+1)*128+ch]
           + x.z*W2[(i2+2)*128+ch] + x.w*W2[(i2+3)*128+ch];
    }
    h2[(size_t)bidd*128 + ch] = fmaxf(s + b2[ch], 0.f);
}

// ---------------- edge scores via split-bf16 MFMA, fragment-pipelined:
// loads(kt+1) issue BEFORE kt's jt-loop (latency hidden under ~1200cyc MFMA);
// dec2(kt+1) after. Raw regs 32 VGPR, frag dbuf 32, b3/w4 moved to epilogue.
__global__ __launch_bounds__(512) void k_edge9(
    const int* __restrict__ ei, const float* __restrict__ h2,
    const uint4* __restrict__ w3h, const uint4* __restrict__ w3l,
    const float* __restrict__ b3, const float* __restrict__ w4,
    const float* __restrict__ b4, float* __restrict__ sc)
{
    __shared__ uint4 sBh[2048];   // 32 KB
    __shared__ uint4 sBl[2048];   // 32 KB
    int tid = threadIdx.x;
    int bid = blockIdx.x;                  // < 512
#pragma unroll
    for (int q=0;q<4;++q){
        sBh[q*512+tid] = w3h[q*512+tid];
        sBl[q*512+tid] = w3l[q*512+tid];
    }
    int tb  = bid >> 6;                    // timestep (64 blocks/t)
    int e0b = (bid & 63) * 256;
    int w   = tid >> 6, lane = tid & 63;
    int e0w = e0b + w*32;
    int r16 = lane & 15, g4 = lane >> 4;

    const int* __restrict__ eit = &ei[tb*2*Ee];
    int a0 = eit[e0w + r16],      s0 = eit[Ee + e0w + r16];
    int a1 = eit[e0w + 16 + r16], s1 = eit[Ee + e0w + 16 + r16];
    const float* __restrict__ pa0 = &h2[(size_t)(tb*Nn+a0)*128];
    const float* __restrict__ pb0 = &h2[(size_t)(tb*Nn+s0)*128];
    const float* __restrict__ pa1 = &h2[(size_t)(tb*Nn+a1)*128];
    const float* __restrict__ pb1 = &h2[(size_t)(tb*Nn+s1)*128];

    f32x4 acc0[8], acc1[8];
#pragma unroll
    for (int jt=0;jt<8;++jt){
        acc0[jt] = (f32x4){0.f,0.f,0.f,0.f};
        acc1[jt] = (f32x4){0.f,0.f,0.f,0.f};
    }

    float4 rA0,rA1,rB0,rB1,rC0,rC1,rD0,rD1;   // raw chunk: grp0 a/b, grp1 a/b
#define LOADK(kt) { int k0=(kt)*32+g4*8; \
    rA0=*(const float4*)&pa0[k0]; rA1=*(const float4*)&pa0[k0+4]; \
    rB0=*(const float4*)&pb0[k0]; rB1=*(const float4*)&pb0[k0+4]; \
    rC0=*(const float4*)&pa1[k0]; rC1=*(const float4*)&pa1[k0+4]; \
    rD0=*(const float4*)&pb1[k0]; rD1=*(const float4*)&pb1[k0+4]; }

    BU ah0[2], al0[2], ah1[2], al1[2];        // fragment double-buffer
#define DECK(s) { uint4 hq,lq; \
    dec2(rA0.x*rB0.x, rA0.y*rB0.y, hq.x, lq.x); \
    dec2(rA0.z*rB0.z, rA0.w*rB0.w, hq.y, lq.y); \
    dec2(rA1.x*rB1.x, rA1.y*rB1.y, hq.z, lq.z); \
    dec2(rA1.z*rB1.z, rA1.w*rB1.w, hq.w, lq.w); \
    ah0[s].q=hq; al0[s].q=lq; \
    dec2(rC0.x*rD0.x, rC0.y*rD0.y, hq.x, lq.x); \
    dec2(rC0.z*rD0.z, rC0.w*rD0.w, hq.y, lq.y); \
    dec2(rC1.x*rD1.x, rC1.y*rD1.y, hq.z, lq.z); \
    dec2(rC1.z*rD1.z, rC1.w*rD1.w, hq.w, lq.w); \
    ah1[s].q=hq; al1[s].q=lq; }

    LOADK(0)
    DECK(0)
    __syncthreads();
#pragma unroll
    for (int kt=0;kt<4;++kt){
        if (kt < 3) LOADK(kt+1)           // issue next chunk before the MFMA window
        const int s = kt & 1;
#pragma unroll
        for (int jt=0;jt<8;++jt){
            BU Bh, Bl;
            Bh.q = sBh[(kt*8+jt)*64 + lane];
            Bl.q = sBl[(kt*8+jt)*64 + lane];
            acc0[jt] = __builtin_amdgcn_mfma_f32_16x16x32_bf16(ah0[s].v, Bh.v, acc0[jt], 0,0,0);
            acc0[jt] = __builtin_amdgcn_mfma_f32_16x16x32_bf16(ah0[s].v, Bl.v, acc0[jt], 0,0,0);
            acc0[jt] = __builtin_amdgcn_mfma_f32_16x16x32_bf16(al0[s].v, Bh.v, acc0[jt], 0,0,0);
            acc1[jt] = __builtin_amdgcn_mfma_f32_16x16x32_bf16(ah1[s].v, Bh.v, acc1[jt], 0,0,0);
            acc1[jt] = __builtin_amdgcn_mfma_f32_16x16x32_bf16(ah1[s].v, Bl.v, acc1[jt], 0,0,0);
            acc1[jt] = __builtin_amdgcn_mfma_f32_16x16x32_bf16(al1[s].v, Bh.v, acc1[jt], 0,0,0);
        }
        if (kt < 3) DECK((kt+1)&1)        // convert after the window: loads have landed
    }

    float b4v = b4[0];
    float b3v[8], w4v[8];
#pragma unroll
    for (int jt=0;jt<8;++jt){ b3v[jt] = b3[jt*16 + r16]; w4v[jt] = w4[jt*16 + r16]; }
#pragma unroll
    for (int r=0;r<4;++r){
        float p0 = 0.f, p1 = 0.f;
#pragma unroll
        for (int jt=0;jt<8;++jt){
            p0 += fmaxf(acc0[jt][r] + b3v[jt], 0.f) * w4v[jt];
            p1 += fmaxf(acc1[jt][r] + b3v[jt], 0.f) * w4v[jt];
        }
        p0 += __shfl_xor(p0,1); p0 += __shfl_xor(p0,2);
        p0 += __shfl_xor(p0,4); p0 += __shfl_xor(p0,8);
        p1 += __shfl_xor(p1,1); p1 += __shfl_xor(p1,2);
        p1 += __shfl_xor(p1,4); p1 += __shfl_xor(p1,8);
        if (r16 == 0){
            sc[(size_t)tb*Ee + e0w + g4*4 + r]      = p0 + b4v;
            sc[(size_t)tb*Ee + e0w + 16 + g4*4 + r] = p1 + b4v;
        }
    }
}

// ---------------- SSM recurrence (reads tag+sc directly)
__global__ __launch_bounds__(256) void k_ssm2(
    const int* __restrict__ ei, const int* __restrict__ tag,
    const float* __restrict__ sc,
    const float* __restrict__ W_in, const float* __restrict__ conv_w,
    const float* __restrict__ conv_b, const float* __restrict__ dt_bias,
    const float* __restrict__ A_log, const float* __restrict__ D_skip,
    const float* __restrict__ W_out, float* __restrict__ out)
{
    __shared__ float scw[132], scb[33], swin[35];
    int tid = threadIdx.x;
    if (tid < 132) scw[tid] = conv_w[tid];
    if (tid < 33)  scb[tid] = conv_b[tid];
    if (tid < 35)  swin[tid] = W_in[tid];
    __syncthreads();

    int e = blockIdx.x*256 + tid;              // < E
    int a = ei[7*2*Ee + e], b = ei[7*2*Ee + Ee + e];
    int cell = a*Nn + b;
    float x[8];
#pragma unroll
    for (int t=0;t<8;++t){
        int tg = tag[t*NNc + cell];
        x[t] = (tg > 0) ? sc[tg-1] : 0.f;
    }

    float A    = -expf(A_log[0]);
    float dtb  = dt_bias[0];
    float dsk  = D_skip[0];
    float wout = W_out[0];
    float win_z = swin[0], win_dt = swin[34];

    float ssm[16];
#pragma unroll
    for (int q=0;q<16;++q) ssm[q]=0.f;
    float h0=0.f,h1=0.f,h2v=0.f;
    float y=0.f;
    for (int t=0;t<8;++t){
        float xt = x[t];
        float act[33];
#pragma unroll
        for (int c=0;c<33;++c){
            float s = h0*scw[c*4+0] + h1*scw[c*4+1] + h2v*scw[c*4+2] + xt*scw[c*4+3];
            float pre = swin[1+c]*s + scb[c];
            act[c] = pre / (1.f + expf(-pre));
        }
        float x_ = act[0];
        float dtr = xt*win_dt + dtb;
        float dt  = (dtr > 20.f) ? dtr : log1pf(expf(dtr));
        float dA  = expf(dt*A);
        float dx  = dt*x_;
        float yv = 0.f;
#pragma unroll
        for (int q=0;q<16;++q){
            ssm[q] = ssm[q]*dA + dx*act[1+q];
            yv += ssm[q]*act[17+q];
        }
        yv += dsk*x_;
        float z = xt*win_z;
        yv *= z / (1.f + expf(-z));
        y = yv;
        h0=h1; h1=h2v; h2v=xt;
    }
    out[cell] = y*wout;
}

extern "C" void kernel_launch(void* const* d_in, const int* in_sizes, int n_in,
                              void* d_out, int out_size, void* d_ws, size_t ws_size,
                              hipStream_t stream)
{
    const int*   ei    = (const int*)d_in[0];
    const float* ew    = (const float*)d_in[1];
    const float* feats = (const float*)d_in[2];
    const float* noise = (const float*)d_in[3];
    const float* Wp1=(const float*)d_in[4];  const float* bp1=(const float*)d_in[5];
    const float* Wp2=(const float*)d_in[6];  const float* bp2=(const float*)d_in[7];
    const float* W1 =(const float*)d_in[8];  const float* b1 =(const float*)d_in[9];
    const float* W2 =(const float*)d_in[10]; const float* b2 =(const float*)d_in[11];
    const float* W3 =(const float*)d_in[12]; const float* b3 =(const float*)d_in[13];
    const float* w4 =(const float*)d_in[14]; const float* b4 =(const float*)d_in[15];
    const float* W_in  =(const float*)d_in[16]; const float* conv_w=(const float*)d_in[17];
    const float* conv_b=(const float*)d_in[18]; const float* dt_bias=(const float*)d_in[19];
    const float* A_log =(const float*)d_in[20]; const float* D_skip=(const float*)d_in[21];
    const float* W_out =(const float*)d_in[22];

    float* out = (float*)d_out;
    float* ws  = (float*)d_ws;
    float* hh    = ws;                      // T*N*128  = 524288
    float* h2    = hh    + 524288;          // 524288
    float* sc    = h2    + 524288;          // T*E      = 131072
    int*   cnt   = (int*)(sc + 131072);     // T*N      = 4096
    int*   tag   = cnt + TNr;               // T*N*N    = 2097152
    int2*  bucket2 = (int2*)(tag + 2097152);           // T*N*CAP int2 = 4MB
    unsigned short* w3h = (unsigned short*)(bucket2 + (size_t)TNr*CAP);  // 16384
    unsigned short* w3l = w3h + 16384;      // 16384

    k_pf      <<<320, 256, 0, stream>>>(ei, W3, w3h, w3l, cnt, tag, (float4*)out,
                                        feats, noise, Wp1, bp1, Wp2, bp2, W1, b1, hh);
    k_histtag <<<TE/256, 256, 0, stream>>>(ei, ew, cnt, bucket2, tag);
    k_sw      <<<TNr/2, 256, 0, stream>>>(hh, cnt, bucket2, W2, b2, h2);
    k_edge9   <<<512, 512, 0, stream>>>(ei, h2, (const uint4*)w3h, (const uint4*)w3l,
                                        b3, w4, b4, sc);
    k_ssm2    <<<Ee/256, 256, 0, stream>>>(ei, tag, sc, W_in, conv_w, conv_b,
                                           dt_bias, A_log, D_skip, W_out, out);
}